// Round 1
// baseline (1663.853 us; speedup 1.0000x reference)
//
#include <hip/hip_runtime.h>
#include <cstdint>
#include <cstddef>

#define MI_NN 16384
#define DIS_NN 8192
#define EMB 128
#define EMM (MI_NN*32)
#define EDD (DIS_NN*32)

typedef __attribute__((ext_vector_type(8))) short short8;
typedef __attribute__((ext_vector_type(4))) float f32x4;

__device__ __forceinline__ float leakyr(float x){ return x > 0.f ? x : 0.2f*x; }
__device__ __forceinline__ float eluf(float x){ return x > 0.f ? x : expm1f(x); }

__device__ __forceinline__ unsigned fenc(float f){
  unsigned u = __float_as_uint(f);
  return (u & 0x80000000u) ? ~u : (u | 0x80000000u);
}
__device__ __forceinline__ float fdec(unsigned u){
  unsigned b = (u & 0x80000000u) ? (u & 0x7FFFFFFFu) : ~u;
  return __uint_as_float(b);
}
__device__ __forceinline__ short bf16r(float x){
  unsigned u = __float_as_uint(x);
  return (short)((u + 0x7FFFu + ((u >> 16) & 1u)) >> 16);
}

// ---------------- CSR build ----------------
__global__ __launch_bounds__(256) void k_count(const int* __restrict__ col,
                                               int* __restrict__ cnt, int E){
  int t = blockIdx.x*256 + threadIdx.x;
  if (t < E) atomicAdd(&cnt[col[t]], 1);
}

__global__ __launch_bounds__(1024) void k_scan(const int* __restrict__ cnt,
                                               int* __restrict__ rowptr, int n, int E){
  __shared__ int lds[1024];
  int t = threadIdx.x;
  int chunk = n >> 10;               // 16 (MM) or 8 (DD)
  int base = t*chunk;
  int s = 0;
  for (int i = 0; i < chunk; ++i) s += cnt[base+i];
  lds[t] = s; __syncthreads();
  for (int off = 1; off < 1024; off <<= 1){
    int v = (t >= off) ? lds[t-off] : 0;
    __syncthreads();
    lds[t] += v;
    __syncthreads();
  }
  int run = lds[t] - s;
  for (int i = 0; i < chunk; ++i){ rowptr[base+i] = run; run += cnt[base+i]; }
  if (t == 0) rowptr[n] = E;
}

__global__ __launch_bounds__(256) void k_fill(const int* __restrict__ col,
                                              const int* __restrict__ rowptr,
                                              int* __restrict__ fill,
                                              int* __restrict__ eidx, int E){
  int t = blockIdx.x*256 + threadIdx.x;
  if (t < E){
    int c = col[t];
    int p = rowptr[c] + atomicAdd(&fill[c], 1);
    eidx[p] = t;
  }
}

// ---------------- dense h = x @ w  (n x 128 by 128 x 128, fp32) ----------------
__global__ __launch_bounds__(256) void k_gemm_xw(const float* __restrict__ X,
                                                 const float* __restrict__ W,
                                                 float* __restrict__ H, int n){
  __shared__ float wl[EMB*EMB];      // 64 KiB
  int t = threadIdx.x;
  {
    const float4* W4 = (const float4*)W;
    float4* L4 = (float4*)wl;
    #pragma unroll
    for (int i = 0; i < 16; ++i) L4[t + 256*i] = W4[t + 256*i];
  }
  __syncthreads();
  int jg = t & 31;                   // 4-col group
  int rg = t >> 5;                   // 0..7
  int r0 = blockIdx.x*32 + rg*4;
  f32x4 acc0 = {0,0,0,0}, acc1 = {0,0,0,0}, acc2 = {0,0,0,0}, acc3 = {0,0,0,0};
  const float4* X4 = (const float4*)X;
  for (int k4 = 0; k4 < 32; ++k4){
    float4 x0 = X4[(size_t)(r0+0)*32 + k4];
    float4 x1 = X4[(size_t)(r0+1)*32 + k4];
    float4 x2 = X4[(size_t)(r0+2)*32 + k4];
    float4 x3 = X4[(size_t)(r0+3)*32 + k4];
#define GSTEP(c0,c1,c2,c3,kq) { f32x4 w4 = *(const f32x4*)&wl[(kq)*EMB + jg*4]; \
      acc0 += (c0)*w4; acc1 += (c1)*w4; acc2 += (c2)*w4; acc3 += (c3)*w4; }
    GSTEP(x0.x, x1.x, x2.x, x3.x, k4*4+0)
    GSTEP(x0.y, x1.y, x2.y, x3.y, k4*4+1)
    GSTEP(x0.z, x1.z, x2.z, x3.z, k4*4+2)
    GSTEP(x0.w, x1.w, x2.w, x3.w, k4*4+3)
#undef GSTEP
  }
  float* out = H + (size_t)r0*EMB + jg*4;
  *(f32x4*)(out)         = acc0;
  *(f32x4*)(out + EMB)   = acc1;
  *(f32x4*)(out + 2*EMB) = acc2;
  *(f32x4*)(out + 3*EMB) = acc3;
}

// ---------------- GCN degree (sym norm) ----------------
__global__ __launch_bounds__(256) void k_deg(const int* __restrict__ rowptr,
                                             const int* __restrict__ eidx,
                                             const float* __restrict__ ew,
                                             float* __restrict__ dinv, int n){
  int v = blockIdx.x*256 + threadIdx.x;
  if (v >= n) return;
  int beg = rowptr[v], end = rowptr[v+1];
  float d = 1.0f;                    // self loop weight
  if (ew){
    for (int i = beg; i < end; ++i) d += ew[eidx[i]];
  } else {
    d += (float)(end - beg);
  }
  dinv[v] = 1.0f / sqrtf(d);
}

// ---------------- GCN aggregation: wave per node ----------------
__global__ __launch_bounds__(256) void k_gcn_agg(const float* __restrict__ H,
    const float* __restrict__ dinv, const int* __restrict__ rowptr,
    const int* __restrict__ eidx, const int* __restrict__ erow,
    const float* __restrict__ ew, const float* __restrict__ bias,
    float* __restrict__ xnext, float* __restrict__ fea, int n, int femode){
  int wid = (int)((blockIdx.x*blockDim.x + threadIdx.x) >> 6);
  int lane = threadIdx.x & 63;
  if (wid >= n) return;
  int v = wid;
  const float2* H2 = (const float2*)H;
  float dv = dinv[v];
  float2 hv = H2[(size_t)v*64 + lane];
  float sw = dv*dv;
  float ax = sw*hv.x, ay = sw*hv.y;
  int beg = rowptr[v], end = rowptr[v+1];
  for (int i = beg; i < end; ++i){
    int e = eidx[i];
    int r = erow[e];
    float w = ew ? ew[e] : 1.0f;
    float nm = dinv[r]*w*dv;
    float2 hr = H2[(size_t)r*64 + lane];
    ax += nm*hr.x; ay += nm*hr.y;
  }
  float2 b2 = ((const float2*)bias)[lane];
  float ox = eluf(ax + b2.x), oy = eluf(ay + b2.y);
  ((float2*)xnext)[(size_t)v*64 + lane] = make_float2(ox, oy);
  float2* F2 = (float2*)fea;
  if (femode == 0){
    F2[(size_t)v*64 + lane] = make_float2(ox, oy);
  } else {
    float2 f = F2[(size_t)v*64 + lane];
    F2[(size_t)v*64 + lane] = make_float2(f.x + ox, f.y + oy);
  }
}

// ---------------- GAT: per-node src/dst scores ----------------
__global__ __launch_bounds__(256) void k_srcdst(const float* __restrict__ H,
    const float* __restrict__ asrc, const float* __restrict__ adst,
    float* __restrict__ es, float* __restrict__ ed, int n){
  int wid = (int)((blockIdx.x*blockDim.x + threadIdx.x) >> 6);
  int lane = threadIdx.x & 63;
  if (wid >= n) return;
  const float2* H2 = (const float2*)H;
  float2 hv = H2[(size_t)wid*64 + lane];
  float2 s2 = ((const float2*)asrc)[lane];
  float2 d2 = ((const float2*)adst)[lane];
  float ps = hv.x*s2.x + hv.y*s2.y;
  float pd = hv.x*d2.x + hv.y*d2.y;
  #pragma unroll
  for (int off = 32; off; off >>= 1){
    ps += __shfl_xor(ps, off);
    pd += __shfl_xor(pd, off);
  }
  if (lane == 0){ es[wid] = ps; ed[wid] = pd; }
}

// ---------------- GAT aggregation: wave per node, online softmax ----------------
__global__ __launch_bounds__(256) void k_gat_agg(const float* __restrict__ H,
    const float* __restrict__ es, const float* __restrict__ ed,
    const int* __restrict__ rowptr, const int* __restrict__ eidx,
    const int* __restrict__ erow, const float* __restrict__ bias,
    float* __restrict__ fea, int n){
  int wid = (int)((blockIdx.x*blockDim.x + threadIdx.x) >> 6);
  int lane = threadIdx.x & 63;
  if (wid >= n) return;
  int v = wid;
  float edv = ed[v];
  float self_e = leakyr(es[v] + edv);
  int beg = rowptr[v], end = rowptr[v+1];
  // pass 1: max (lane-strided)
  float m = self_e;
  for (int i = beg + lane; i < end; i += 64){
    int e = eidx[i]; int r = erow[e];
    m = fmaxf(m, leakyr(es[r] + edv));
  }
  #pragma unroll
  for (int off = 32; off; off >>= 1) m = fmaxf(m, __shfl_xor(m, off));
  // pass 2: denom
  float s = 0.f;
  for (int i = beg + lane; i < end; i += 64){
    int e = eidx[i]; int r = erow[e];
    s += expf(leakyr(es[r] + edv) - m);
  }
  #pragma unroll
  for (int off = 32; off; off >>= 1) s += __shfl_xor(s, off);
  s += expf(self_e - m);
  float inv_s = 1.0f / s;
  // pass 3: features (lane-uniform over edges, lane = 2 channels)
  const float2* H2 = (const float2*)H;
  float2 hv = H2[(size_t)v*64 + lane];
  float a0 = expf(self_e - m)*inv_s;
  float ax = a0*hv.x, ay = a0*hv.y;
  for (int i = beg; i < end; ++i){
    int e = eidx[i]; int r = erow[e];
    float a = expf(leakyr(es[r] + edv) - m)*inv_s;
    float2 hr = H2[(size_t)r*64 + lane];
    ax += a*hr.x; ay += a*hr.y;
  }
  float2 b2 = ((const float2*)bias)[lane];
  float ox = eluf(ax + b2.x), oy = eluf(ay + b2.y);
  float2* F2 = (float2*)fea;
  float2 f = F2[(size_t)v*64 + lane];
  F2[(size_t)v*64 + lane] = make_float2((f.x + ox)/3.0f, (f.y + oy)/3.0f);
}

// ---------------- score GEMM: S = A (16384x128) @ B^T (8192x128), bf16 MFMA ----------------
__device__ __forceinline__ short8 pack8(float4 a, float4 b){
  short8 r;
  r[0] = bf16r(a.x); r[1] = bf16r(a.y); r[2] = bf16r(a.z); r[3] = bf16r(a.w);
  r[4] = bf16r(b.x); r[5] = bf16r(b.y); r[6] = bf16r(b.z); r[7] = bf16r(b.w);
  return r;
}

__global__ __launch_bounds__(256) void k_score(const float* __restrict__ A,
                                               const float* __restrict__ B,
                                               float* __restrict__ S,
                                               unsigned* __restrict__ mmx){
  int lane = threadIdx.x & 63;
  int w = threadIdx.x >> 6;          // 0..3
  int wr = w >> 1, wc = w & 1;
  int i0 = blockIdx.y*128 + wr*64;
  int j0 = blockIdx.x*128 + wc*64;
  int lr = lane & 15;
  int lk = lane >> 4;                // k-quarter
  f32x4 acc[4][4];
  #pragma unroll
  for (int a = 0; a < 4; ++a)
    #pragma unroll
    for (int b = 0; b < 4; ++b) acc[a][b] = (f32x4){0.f,0.f,0.f,0.f};

  for (int k0 = 0; k0 < 128; k0 += 32){
    int kk = k0 + lk*8;
    short8 af[4], bf[4];
    #pragma unroll
    for (int t = 0; t < 4; ++t){
      const float4* pa = (const float4*)(A + (size_t)(i0 + t*16 + lr)*EMB + kk);
      af[t] = pack8(pa[0], pa[1]);
      const float4* pb = (const float4*)(B + (size_t)(j0 + t*16 + lr)*EMB + kk);
      bf[t] = pack8(pb[0], pb[1]);
    }
    #pragma unroll
    for (int rt = 0; rt < 4; ++rt)
      #pragma unroll
      for (int ct = 0; ct < 4; ++ct)
        acc[rt][ct] = __builtin_amdgcn_mfma_f32_16x16x32_bf16(af[rt], bf[ct], acc[rt][ct], 0, 0, 0);
  }

  float lmin = 3.4e38f, lmax = -3.4e38f;
  #pragma unroll
  for (int rt = 0; rt < 4; ++rt){
    #pragma unroll
    for (int ct = 0; ct < 4; ++ct){
      int colj = j0 + ct*16 + lr;
      int row0 = i0 + rt*16 + lk*4;
      #pragma unroll
      for (int q = 0; q < 4; ++q){
        float v = acc[rt][ct][q];
        S[(size_t)(row0+q)*DIS_NN + colj] = v;
        lmin = fminf(lmin, v); lmax = fmaxf(lmax, v);
      }
    }
  }
  #pragma unroll
  for (int off = 32; off; off >>= 1){
    lmin = fminf(lmin, __shfl_xor(lmin, off));
    lmax = fmaxf(lmax, __shfl_xor(lmax, off));
  }
  if (lane == 0){
    atomicMin(&mmx[0], fenc(lmin));
    atomicMax(&mmx[1], fenc(lmax));
  }
}

__global__ void k_minmax_init(unsigned* mmx){
  mmx[0] = 0xFFFFFFFFu;   // encoded min tracker
  mmx[1] = 0u;            // encoded max tracker
}

__global__ __launch_bounds__(256) void k_norm(float4* __restrict__ S4,
                                              const unsigned* __restrict__ mmx, int n4){
  float mn = fdec(mmx[0]);
  float mx = fdec(mmx[1]);
  float sc = (mx > mn) ? 1.0f/(mx - mn) : 0.0f;
  int idx = blockIdx.x*blockDim.x + threadIdx.x;
  int stride = gridDim.x*blockDim.x;
  for (int i = idx; i < n4; i += stride){
    float4 v = S4[i];
    v.x = fminf(fmaxf((v.x - mn)*sc, 0.f), 1.f);
    v.y = fminf(fmaxf((v.y - mn)*sc, 0.f), 1.f);
    v.z = fminf(fmaxf((v.z - mn)*sc, 0.f), 1.f);
    v.w = fminf(fmaxf((v.w - mn)*sc, 0.f), 1.f);
    S4[i] = v;
  }
}

// ---------------- host ----------------
struct GraphPtrs {
  const float *x0, *ew, *w1, *b1, *w2, *b2, *w3, *asrc, *adst, *b3;
  const int* edges;
  float* fea;
  int n, E;
};

static void run_graph(const GraphPtrs& g, float* A0, float* A1, float* Hb,
                      float* DEG, float* ES, float* ED,
                      int* CNT, int* ROWPTR, int* FILL, int* EIDX,
                      hipStream_t stream){
  const int n = g.n, E = g.E;
  const int* erow = g.edges;
  const int* ecol = g.edges + E;
  hipMemsetAsync(CNT, 0, (size_t)n*sizeof(int), stream);
  k_count<<<(E+255)/256, 256, 0, stream>>>(ecol, CNT, E);
  k_scan<<<1, 1024, 0, stream>>>(CNT, ROWPTR, n, E);
  hipMemsetAsync(FILL, 0, (size_t)n*sizeof(int), stream);
  k_fill<<<(E+255)/256, 256, 0, stream>>>(ecol, ROWPTR, FILL, EIDX, E);
  // layer 1: GCN with edge weights
  k_gemm_xw<<<n/32, 256, 0, stream>>>(g.x0, g.w1, Hb, n);
  k_deg<<<(n+255)/256, 256, 0, stream>>>(ROWPTR, EIDX, g.ew, DEG, n);
  k_gcn_agg<<<n/4, 256, 0, stream>>>(Hb, DEG, ROWPTR, EIDX, erow, g.ew, g.b1, A0, g.fea, n, 0);
  // layer 2: GCN, unit weights
  k_gemm_xw<<<n/32, 256, 0, stream>>>(A0, g.w2, Hb, n);
  k_deg<<<(n+255)/256, 256, 0, stream>>>(ROWPTR, EIDX, nullptr, DEG, n);
  k_gcn_agg<<<n/4, 256, 0, stream>>>(Hb, DEG, ROWPTR, EIDX, erow, nullptr, g.b2, A1, g.fea, n, 1);
  // layer 3: GAT
  k_gemm_xw<<<n/32, 256, 0, stream>>>(A1, g.w3, Hb, n);
  k_srcdst<<<n/4, 256, 0, stream>>>(Hb, g.asrc, g.adst, ES, ED, n);
  k_gat_agg<<<n/4, 256, 0, stream>>>(Hb, ES, ED, ROWPTR, EIDX, erow, g.b3, g.fea, n);
}

extern "C" void kernel_launch(void* const* d_in, const int* in_sizes, int n_in,
                              void* d_out, int out_size, void* d_ws, size_t ws_size,
                              hipStream_t stream){
  (void)in_sizes; (void)n_in; (void)out_size; (void)ws_size;
  const float* mm_x0  = (const float*)d_in[0];
  const float* dd_x0  = (const float*)d_in[1];
  const float* w1_mm  = (const float*)d_in[2];
  const float* b1_mm  = (const float*)d_in[3];
  const float* w2_mm  = (const float*)d_in[4];
  const float* b2_mm  = (const float*)d_in[5];
  const float* w3_mm  = (const float*)d_in[6];
  const float* asrc_mm= (const float*)d_in[7];
  const float* adst_mm= (const float*)d_in[8];
  const float* b3_mm  = (const float*)d_in[9];
  const float* w1_dd  = (const float*)d_in[10];
  const float* b1_dd  = (const float*)d_in[11];
  const float* w2_dd  = (const float*)d_in[12];
  const float* b2_dd  = (const float*)d_in[13];
  const float* w3_dd  = (const float*)d_in[14];
  const float* asrc_dd= (const float*)d_in[15];
  const float* adst_dd= (const float*)d_in[16];
  const float* b3_dd  = (const float*)d_in[17];
  const float* mm_ew  = (const float*)d_in[18];
  const float* dd_ew  = (const float*)d_in[19];
  const int* mm_edges = (const int*)d_in[20];
  const int* dd_edges = (const int*)d_in[21];

  float* S = (float*)d_out;
  const size_t SLOT = (size_t)MI_NN * EMB;          // 2097152 floats
  // scratch carved out of the score region (overwritten at the very end)
  float* A0  = S;
  float* A1  = S + SLOT;
  float* Hb  = S + 2*SLOT;
  float* DEG = S + 3*SLOT;
  float* ES  = DEG + MI_NN;
  float* ED  = ES + MI_NN;
  int* CNT    = (int*)(ED + MI_NN);
  int* ROWPTR = CNT + (MI_NN + 64);
  int* FILL   = ROWPTR + (MI_NN + 64);
  int* EIDX   = FILL + (MI_NN + 64);
  float* FEA_MI  = S + (size_t)MI_NN * DIS_NN;      // output slot 2
  float* FEA_DIS = FEA_MI + SLOT;                   // output slot 3
  unsigned* MMX = (unsigned*)d_ws;

  GraphPtrs gm{mm_x0, mm_ew, w1_mm, b1_mm, w2_mm, b2_mm, w3_mm, asrc_mm, adst_mm, b3_mm,
               mm_edges, FEA_MI, MI_NN, EMM};
  run_graph(gm, A0, A1, Hb, DEG, ES, ED, CNT, ROWPTR, FILL, EIDX, stream);

  GraphPtrs gd{dd_x0, dd_ew, w1_dd, b1_dd, w2_dd, b2_dd, w3_dd, asrc_dd, adst_dd, b3_dd,
               dd_edges, FEA_DIS, DIS_NN, EDD};
  run_graph(gd, A0, A1, Hb, DEG, ES, ED, CNT, ROWPTR, FILL, EIDX, stream);

  k_minmax_init<<<1, 1, 0, stream>>>(MMX);
  k_score<<<dim3(DIS_NN/128, MI_NN/128), 256, 0, stream>>>(FEA_MI, FEA_DIS, S, MMX);
  k_norm<<<4096, 256, 0, stream>>>((float4*)S, MMX, (MI_NN*DIS_NN)/4);
}

// Round 2
// 1308.247 us; speedup vs baseline: 1.2718x; 1.2718x over previous
//
#include <hip/hip_runtime.h>
#include <cstdint>
#include <cstddef>

#define MI_NN 16384
#define DIS_NN 8192
#define EMB 128
#define EMM (MI_NN*32)
#define EDD (DIS_NN*32)

typedef __attribute__((ext_vector_type(8))) short short8;
typedef __attribute__((ext_vector_type(4))) float f32x4;

__device__ __forceinline__ float leakyr(float x){ return x > 0.f ? x : 0.2f*x; }
__device__ __forceinline__ float eluf(float x){ return x > 0.f ? x : expm1f(x); }

__device__ __forceinline__ unsigned fenc(float f){
  unsigned u = __float_as_uint(f);
  return (u & 0x80000000u) ? ~u : (u | 0x80000000u);
}
__device__ __forceinline__ float fdec(unsigned u){
  unsigned b = (u & 0x80000000u) ? (u & 0x7FFFFFFFu) : ~u;
  return __uint_as_float(b);
}
__device__ __forceinline__ unsigned bf16u(float x){
  unsigned u = __float_as_uint(x);
  return (u + 0x7FFFu + ((u >> 16) & 1u)) >> 16;   // RNE
}

// ---------------- CSR build ----------------
__global__ __launch_bounds__(256) void k_count(const int* __restrict__ col,
                                               int* __restrict__ cnt, int E){
  int t = blockIdx.x*256 + threadIdx.x;
  if (t < E) atomicAdd(&cnt[col[t]], 1);
}

__global__ __launch_bounds__(1024) void k_scan(const int* __restrict__ cnt,
                                               int* __restrict__ rowptr, int n, int E){
  __shared__ int lds[1024];
  int t = threadIdx.x;
  int chunk = n >> 10;
  int base = t*chunk;
  int s = 0;
  for (int i = 0; i < chunk; ++i) s += cnt[base+i];
  lds[t] = s; __syncthreads();
  for (int off = 1; off < 1024; off <<= 1){
    int v = (t >= off) ? lds[t-off] : 0;
    __syncthreads();
    lds[t] += v;
    __syncthreads();
  }
  int run = lds[t] - s;
  for (int i = 0; i < chunk; ++i){ rowptr[base+i] = run; run += cnt[base+i]; }
  if (t == 0) rowptr[n] = E;
}

__global__ __launch_bounds__(256) void k_fill2(const int* __restrict__ row,
                                               const int* __restrict__ col,
                                               const float* __restrict__ ew,
                                               const int* __restrict__ rowptr,
                                               int* __restrict__ fill,
                                               int* __restrict__ esrc,
                                               float* __restrict__ ewv, int E){
  int t = blockIdx.x*256 + threadIdx.x;
  if (t < E){
    int c = col[t];
    int p = rowptr[c] + atomicAdd(&fill[c], 1);
    esrc[p] = row[t];
    ewv[p] = ew[t];
  }
}

// ---------------- dense h = x @ w  (n x 128 by 128 x 128, fp32) ----------------
__global__ __launch_bounds__(256) void k_gemm_xw(const float* __restrict__ X,
                                                 const float* __restrict__ W,
                                                 float* __restrict__ H, int n){
  __shared__ float wl[EMB*EMB];
  int t = threadIdx.x;
  {
    const float4* W4 = (const float4*)W;
    float4* L4 = (float4*)wl;
    #pragma unroll
    for (int i = 0; i < 16; ++i) L4[t + 256*i] = W4[t + 256*i];
  }
  __syncthreads();
  int jg = t & 31;
  int rg = t >> 5;
  int r0 = blockIdx.x*32 + rg*4;
  f32x4 acc0 = {0,0,0,0}, acc1 = {0,0,0,0}, acc2 = {0,0,0,0}, acc3 = {0,0,0,0};
  const float4* X4 = (const float4*)X;
  for (int k4 = 0; k4 < 32; ++k4){
    float4 x0 = X4[(size_t)(r0+0)*32 + k4];
    float4 x1 = X4[(size_t)(r0+1)*32 + k4];
    float4 x2 = X4[(size_t)(r0+2)*32 + k4];
    float4 x3 = X4[(size_t)(r0+3)*32 + k4];
#define GSTEP(c0,c1,c2,c3,kq) { f32x4 w4 = *(const f32x4*)&wl[(kq)*EMB + jg*4]; \
      acc0 += (c0)*w4; acc1 += (c1)*w4; acc2 += (c2)*w4; acc3 += (c3)*w4; }
    GSTEP(x0.x, x1.x, x2.x, x3.x, k4*4+0)
    GSTEP(x0.y, x1.y, x2.y, x3.y, k4*4+1)
    GSTEP(x0.z, x1.z, x2.z, x3.z, k4*4+2)
    GSTEP(x0.w, x1.w, x2.w, x3.w, k4*4+3)
#undef GSTEP
  }
  float* out = H + (size_t)r0*EMB + jg*4;
  *(f32x4*)(out)         = acc0;
  *(f32x4*)(out + EMB)   = acc1;
  *(f32x4*)(out + 2*EMB) = acc2;
  *(f32x4*)(out + 3*EMB) = acc3;
}

// ---------------- degree / per-edge norm prep ----------------
__global__ __launch_bounds__(256) void k_deg1(const int* __restrict__ rowptr,
                                              const float* __restrict__ ewv,
                                              float* __restrict__ dinv, int n){
  int wid = (int)((blockIdx.x*blockDim.x + threadIdx.x) >> 6);
  int lane = threadIdx.x & 63;
  if (wid >= n) return;
  int beg = rowptr[wid], end = rowptr[wid+1];
  float s = 0.f;
  for (int i = beg + lane; i < end; i += 64) s += ewv[i];
  #pragma unroll
  for (int off = 32; off; off >>= 1) s += __shfl_xor(s, off);
  if (lane == 0) dinv[wid] = rsqrtf(1.0f + s);
}

__global__ __launch_bounds__(256) void k_deg2(const int* __restrict__ rowptr,
                                              float* __restrict__ dinv, int n){
  int v = blockIdx.x*256 + threadIdx.x;
  if (v < n) dinv[v] = rsqrtf(1.0f + (float)(rowptr[v+1] - rowptr[v]));
}

__global__ __launch_bounds__(256) void k_edgenorm1(const int* __restrict__ esrc,
                                                   const float* __restrict__ ewv,
                                                   const float* __restrict__ dinv,
                                                   float* __restrict__ nrm, int E){
  int t = blockIdx.x*256 + threadIdx.x;
  if (t < E) nrm[t] = dinv[esrc[t]] * ewv[t];
}

__global__ __launch_bounds__(256) void k_edgenorm2(const int* __restrict__ esrc,
                                                   const float* __restrict__ dinv,
                                                   float* __restrict__ nrm, int E){
  int t = blockIdx.x*256 + threadIdx.x;
  if (t < E) nrm[t] = dinv[esrc[t]];
}

__global__ __launch_bounds__(256) void k_esv(const int* __restrict__ esrc,
                                             const float* __restrict__ es,
                                             float* __restrict__ esv, int E){
  int t = blockIdx.x*256 + threadIdx.x;
  if (t < E) esv[t] = es[esrc[t]];
}

// ---------------- GCN aggregation: wave per node ----------------
__global__ __launch_bounds__(256) void k_gcn_agg2(const float* __restrict__ H,
    const float* __restrict__ dinv, const int* __restrict__ rowptr,
    const int* __restrict__ esrc, const float* __restrict__ nrm,
    const float* __restrict__ bias,
    float* __restrict__ xnext, float* __restrict__ fea, int n, int femode){
  int wid = (int)((blockIdx.x*blockDim.x + threadIdx.x) >> 6);
  int lane = threadIdx.x & 63;
  if (wid >= n) return;
  int v = wid;
  const float2* H2 = (const float2*)H;
  float dv = dinv[v];
  float2 hv = H2[(size_t)v*64 + lane];
  float ax = dv*hv.x, ay = dv*hv.y;     // self term (outer dv applied at end)
  int beg = rowptr[v], end = rowptr[v+1];
  int i = beg;
  int e4 = beg + ((end - beg) & ~3);
  for (; i < e4; i += 4){
    int r0 = esrc[i], r1 = esrc[i+1], r2 = esrc[i+2], r3 = esrc[i+3];
    float n0 = nrm[i], n1 = nrm[i+1], n2 = nrm[i+2], n3 = nrm[i+3];
    float2 h0 = H2[(size_t)r0*64 + lane];
    float2 h1 = H2[(size_t)r1*64 + lane];
    float2 h2 = H2[(size_t)r2*64 + lane];
    float2 h3 = H2[(size_t)r3*64 + lane];
    ax += n0*h0.x + n1*h1.x + n2*h2.x + n3*h3.x;
    ay += n0*h0.y + n1*h1.y + n2*h2.y + n3*h3.y;
  }
  for (; i < end; ++i){
    int r = esrc[i];
    float nm = nrm[i];
    float2 hr = H2[(size_t)r*64 + lane];
    ax += nm*hr.x; ay += nm*hr.y;
  }
  float2 b2 = ((const float2*)bias)[lane];
  float ox = eluf(dv*ax + b2.x), oy = eluf(dv*ay + b2.y);
  ((float2*)xnext)[(size_t)v*64 + lane] = make_float2(ox, oy);
  float2* F2 = (float2*)fea;
  if (femode == 0){
    F2[(size_t)v*64 + lane] = make_float2(ox, oy);
  } else {
    float2 f = F2[(size_t)v*64 + lane];
    F2[(size_t)v*64 + lane] = make_float2(f.x + ox, f.y + oy);
  }
}

// ---------------- GAT: per-node src/dst scores ----------------
__global__ __launch_bounds__(256) void k_srcdst(const float* __restrict__ H,
    const float* __restrict__ asrc, const float* __restrict__ adst,
    float* __restrict__ es, float* __restrict__ ed, int n){
  int wid = (int)((blockIdx.x*blockDim.x + threadIdx.x) >> 6);
  int lane = threadIdx.x & 63;
  if (wid >= n) return;
  const float2* H2 = (const float2*)H;
  float2 hv = H2[(size_t)wid*64 + lane];
  float2 s2 = ((const float2*)asrc)[lane];
  float2 d2 = ((const float2*)adst)[lane];
  float ps = hv.x*s2.x + hv.y*s2.y;
  float pd = hv.x*d2.x + hv.y*d2.y;
  #pragma unroll
  for (int off = 32; off; off >>= 1){
    ps += __shfl_xor(ps, off);
    pd += __shfl_xor(pd, off);
  }
  if (lane == 0){ es[wid] = ps; ed[wid] = pd; }
}

// ---------------- GAT aggregation ----------------
__global__ __launch_bounds__(256) void k_gat_agg2(const float* __restrict__ H,
    const float* __restrict__ es, const float* __restrict__ ed,
    const int* __restrict__ rowptr, const int* __restrict__ esrc,
    const float* __restrict__ esv, const float* __restrict__ bias,
    float* __restrict__ fea, int n){
  int wid = (int)((blockIdx.x*blockDim.x + threadIdx.x) >> 6);
  int lane = threadIdx.x & 63;
  if (wid >= n) return;
  int v = wid;
  float edv = ed[v];
  float self_e = leakyr(es[v] + edv);
  int beg = rowptr[v], end = rowptr[v+1];
  // pass 1: max (lane-strided, coalesced esv)
  float m = self_e;
  for (int i = beg + lane; i < end; i += 64)
    m = fmaxf(m, leakyr(esv[i] + edv));
  #pragma unroll
  for (int off = 32; off; off >>= 1) m = fmaxf(m, __shfl_xor(m, off));
  // pass 2: denom
  float s = 0.f;
  for (int i = beg + lane; i < end; i += 64)
    s += expf(leakyr(esv[i] + edv) - m);
  #pragma unroll
  for (int off = 32; off; off >>= 1) s += __shfl_xor(s, off);
  s += expf(self_e - m);
  float inv_s = 1.0f / s;
  // pass 3: features (lane = 2 channels), unrolled x4
  const float2* H2 = (const float2*)H;
  float2 hv = H2[(size_t)v*64 + lane];
  float a0 = expf(self_e - m)*inv_s;
  float ax = a0*hv.x, ay = a0*hv.y;
  int i = beg;
  int e4 = beg + ((end - beg) & ~3);
  for (; i < e4; i += 4){
    int r0 = esrc[i], r1 = esrc[i+1], r2 = esrc[i+2], r3 = esrc[i+3];
    float a_0 = expf(leakyr(esv[i]   + edv) - m)*inv_s;
    float a_1 = expf(leakyr(esv[i+1] + edv) - m)*inv_s;
    float a_2 = expf(leakyr(esv[i+2] + edv) - m)*inv_s;
    float a_3 = expf(leakyr(esv[i+3] + edv) - m)*inv_s;
    float2 h0 = H2[(size_t)r0*64 + lane];
    float2 h1 = H2[(size_t)r1*64 + lane];
    float2 h2 = H2[(size_t)r2*64 + lane];
    float2 h3 = H2[(size_t)r3*64 + lane];
    ax += a_0*h0.x + a_1*h1.x + a_2*h2.x + a_3*h3.x;
    ay += a_0*h0.y + a_1*h1.y + a_2*h2.y + a_3*h3.y;
  }
  for (; i < end; ++i){
    int r = esrc[i];
    float a = expf(leakyr(esv[i] + edv) - m)*inv_s;
    float2 hr = H2[(size_t)r*64 + lane];
    ax += a*hr.x; ay += a*hr.y;
  }
  float2 b2 = ((const float2*)bias)[lane];
  float ox = eluf(ax + b2.x), oy = eluf(ay + b2.y);
  float2* F2 = (float2*)fea;
  float2 f = F2[(size_t)v*64 + lane];
  F2[(size_t)v*64 + lane] = make_float2((f.x + ox)/3.0f, (f.y + oy)/3.0f);
}

// ---------------- score GEMM, two-pass (minmax / normalized store) ----------------
// LDS: bf16 128x128 tiles, XOR-swizzled: byte ^= ((row&7)<<4)
template<int STORE>
__global__ __launch_bounds__(256) void k_score2(const float* __restrict__ A,
                                                const float* __restrict__ B,
                                                float* __restrict__ S,
                                                unsigned* __restrict__ mmx){
  __shared__ __align__(16) char Al[128*256];   // 32 KB
  __shared__ __align__(16) char Bl[128*256];   // 32 KB
  const int t = threadIdx.x;
  const int i0b = blockIdx.y*128;
  const int j0b = blockIdx.x*128;

  // stage A and B tiles: fp32 coalesced load -> bf16 -> swizzled LDS
  #pragma unroll
  for (int it = 0; it < 16; ++it){
    int f4 = it*256 + t;               // float4 idx in 128x128 tile
    int row = f4 >> 5;
    int c4  = f4 & 31;
    float4 va = ((const float4*)(A + (size_t)(i0b+row)*EMB))[c4];
    float4 vb = ((const float4*)(B + (size_t)(j0b+row)*EMB))[c4];
    int sw = (row & 7) << 4;
    int off = row*256 + ((c4*8) ^ sw);
    uint2 pa, pb;
    pa.x = bf16u(va.x) | (bf16u(va.y) << 16);
    pa.y = bf16u(va.z) | (bf16u(va.w) << 16);
    pb.x = bf16u(vb.x) | (bf16u(vb.y) << 16);
    pb.y = bf16u(vb.z) | (bf16u(vb.w) << 16);
    *(uint2*)&Al[off] = pa;
    *(uint2*)&Bl[off] = pb;
  }
  __syncthreads();

  const int lane = t & 63;
  const int w = t >> 6;
  const int wr = w >> 1, wc = w & 1;
  const int lr = lane & 15;
  const int lk = lane >> 4;

  f32x4 acc[4][4];
  #pragma unroll
  for (int a = 0; a < 4; ++a)
    #pragma unroll
    for (int b = 0; b < 4; ++b) acc[a][b] = (f32x4){0.f,0.f,0.f,0.f};

  #pragma unroll
  for (int k0 = 0; k0 < 4; ++k0){
    int kb = k0*64 + lk*16;            // byte offset of 8 bf16
    short8 af[4], bf[4];
    #pragma unroll
    for (int tt = 0; tt < 4; ++tt){
      int ra = wr*64 + tt*16 + lr;
      int rb = wc*64 + tt*16 + lr;
      af[tt] = *(const short8*)&Al[ra*256 + (kb ^ ((ra&7)<<4))];
      bf[tt] = *(const short8*)&Bl[rb*256 + (kb ^ ((rb&7)<<4))];
    }
    #pragma unroll
    for (int rt = 0; rt < 4; ++rt)
      #pragma unroll
      for (int ct = 0; ct < 4; ++ct)
        acc[rt][ct] = __builtin_amdgcn_mfma_f32_16x16x32_bf16(af[rt], bf[ct], acc[rt][ct], 0, 0, 0);
  }

  if (STORE){
    float mn = fdec(mmx[0]);
    float mx = fdec(mmx[1]);
    float sc = (mx > mn) ? 1.0f/(mx - mn) : 0.0f;
    int i0 = i0b + wr*64, j0 = j0b + wc*64;
    #pragma unroll
    for (int rt = 0; rt < 4; ++rt){
      #pragma unroll
      for (int ct = 0; ct < 4; ++ct){
        int colj = j0 + ct*16 + lr;
        int row0 = i0 + rt*16 + lk*4;
        #pragma unroll
        for (int q = 0; q < 4; ++q){
          float vv = fminf(fmaxf((acc[rt][ct][q] - mn)*sc, 0.f), 1.f);
          S[(size_t)(row0+q)*DIS_NN + colj] = vv;
        }
      }
    }
  } else {
    float lmin = 3.4e38f, lmax = -3.4e38f;
    #pragma unroll
    for (int rt = 0; rt < 4; ++rt)
      #pragma unroll
      for (int ct = 0; ct < 4; ++ct)
        #pragma unroll
        for (int q = 0; q < 4; ++q){
          float vv = acc[rt][ct][q];
          lmin = fminf(lmin, vv); lmax = fmaxf(lmax, vv);
        }
    #pragma unroll
    for (int off = 32; off; off >>= 1){
      lmin = fminf(lmin, __shfl_xor(lmin, off));
      lmax = fmaxf(lmax, __shfl_xor(lmax, off));
    }
    if (lane == 0){
      atomicMin(&mmx[0], fenc(lmin));
      atomicMax(&mmx[1], fenc(lmax));
    }
  }
}

__global__ void k_minmax_init(unsigned* mmx){
  mmx[0] = 0xFFFFFFFFu;
  mmx[1] = 0u;
}

// ---------------- host ----------------
struct GraphPtrs {
  const float *x0, *ew, *w1, *b1, *w2, *b2, *w3, *asrc, *adst, *b3;
  const int* edges;
  float* fea;
  int n, E;
};

static void run_graph(const GraphPtrs& g, float* A0, float* A1, float* Hb,
                      float* DEG1, float* DEG2, float* ES, float* ED,
                      int* CNT, int* ROWPTR, int* FILL,
                      int* ESRC, float* EWV, float* NORM,
                      hipStream_t stream){
  const int n = g.n, E = g.E;
  const int* erow = g.edges;
  const int* ecol = g.edges + E;
  hipMemsetAsync(CNT, 0, (size_t)n*sizeof(int), stream);
  k_count<<<(E+255)/256, 256, 0, stream>>>(ecol, CNT, E);
  k_scan<<<1, 1024, 0, stream>>>(CNT, ROWPTR, n, E);
  hipMemsetAsync(FILL, 0, (size_t)n*sizeof(int), stream);
  k_fill2<<<(E+255)/256, 256, 0, stream>>>(erow, ecol, g.ew, ROWPTR, FILL, ESRC, EWV, E);
  // layer 1: GCN with edge weights
  k_gemm_xw<<<n/32, 256, 0, stream>>>(g.x0, g.w1, Hb, n);
  k_deg1<<<n/4, 256, 0, stream>>>(ROWPTR, EWV, DEG1, n);
  k_edgenorm1<<<(E+255)/256, 256, 0, stream>>>(ESRC, EWV, DEG1, NORM, E);
  k_gcn_agg2<<<n/4, 256, 0, stream>>>(Hb, DEG1, ROWPTR, ESRC, NORM, g.b1, A0, g.fea, n, 0);
  // layer 2: GCN, unit weights
  k_gemm_xw<<<n/32, 256, 0, stream>>>(A0, g.w2, Hb, n);
  k_deg2<<<(n+255)/256, 256, 0, stream>>>(ROWPTR, DEG2, n);
  k_edgenorm2<<<(E+255)/256, 256, 0, stream>>>(ESRC, DEG2, NORM, E);
  k_gcn_agg2<<<n/4, 256, 0, stream>>>(Hb, DEG2, ROWPTR, ESRC, NORM, g.b2, A1, g.fea, n, 1);
  // layer 3: GAT
  k_gemm_xw<<<n/32, 256, 0, stream>>>(A1, g.w3, Hb, n);
  k_srcdst<<<n/4, 256, 0, stream>>>(Hb, g.asrc, g.adst, ES, ED, n);
  k_esv<<<(E+255)/256, 256, 0, stream>>>(ESRC, ES, NORM, E);   // NORM reused as ESV
  k_gat_agg2<<<n/4, 256, 0, stream>>>(Hb, ES, ED, ROWPTR, ESRC, NORM, g.b3, g.fea, n);
}

extern "C" void kernel_launch(void* const* d_in, const int* in_sizes, int n_in,
                              void* d_out, int out_size, void* d_ws, size_t ws_size,
                              hipStream_t stream){
  (void)in_sizes; (void)n_in; (void)out_size; (void)ws_size;
  const float* mm_x0  = (const float*)d_in[0];
  const float* dd_x0  = (const float*)d_in[1];
  const float* w1_mm  = (const float*)d_in[2];
  const float* b1_mm  = (const float*)d_in[3];
  const float* w2_mm  = (const float*)d_in[4];
  const float* b2_mm  = (const float*)d_in[5];
  const float* w3_mm  = (const float*)d_in[6];
  const float* asrc_mm= (const float*)d_in[7];
  const float* adst_mm= (const float*)d_in[8];
  const float* b3_mm  = (const float*)d_in[9];
  const float* w1_dd  = (const float*)d_in[10];
  const float* b1_dd  = (const float*)d_in[11];
  const float* w2_dd  = (const float*)d_in[12];
  const float* b2_dd  = (const float*)d_in[13];
  const float* w3_dd  = (const float*)d_in[14];
  const float* asrc_dd= (const float*)d_in[15];
  const float* adst_dd= (const float*)d_in[16];
  const float* b3_dd  = (const float*)d_in[17];
  const float* mm_ew  = (const float*)d_in[18];
  const float* dd_ew  = (const float*)d_in[19];
  const int* mm_edges = (const int*)d_in[20];
  const int* dd_edges = (const int*)d_in[21];

  float* S = (float*)d_out;
  const size_t SLOT = (size_t)MI_NN * EMB;
  // scratch carved out of the score region (only overwritten by the final store pass)
  float* A0  = S;
  float* A1  = S + SLOT;
  float* Hb  = S + 2*SLOT;
  float* base = S + 3*SLOT;
  float* DEG1 = base;                     base += MI_NN;
  float* DEG2 = base;                     base += MI_NN;
  float* ES   = base;                     base += MI_NN;
  float* ED   = base;                     base += MI_NN;
  int* CNT    = (int*)base;               base += MI_NN + 64;
  int* ROWPTR = (int*)base;               base += MI_NN + 64;
  int* FILL   = (int*)base;               base += MI_NN + 64;
  int* ESRC   = (int*)base;               base += EMM;
  float* EWV  = base;                     base += EMM;
  float* NORM = base;                     base += EMM;
  float* FEA_MI  = S + (size_t)MI_NN * DIS_NN;
  float* FEA_DIS = FEA_MI + SLOT;
  unsigned* MMX = (unsigned*)d_ws;

  GraphPtrs gm{mm_x0, mm_ew, w1_mm, b1_mm, w2_mm, b2_mm, w3_mm, asrc_mm, adst_mm, b3_mm,
               mm_edges, FEA_MI, MI_NN, EMM};
  run_graph(gm, A0, A1, Hb, DEG1, DEG2, ES, ED, CNT, ROWPTR, FILL, ESRC, EWV, NORM, stream);

  GraphPtrs gd{dd_x0, dd_ew, w1_dd, b1_dd, w2_dd, b2_dd, w3_dd, asrc_dd, adst_dd, b3_dd,
               dd_edges, FEA_DIS, DIS_NN, EDD};
  run_graph(gd, A0, A1, Hb, DEG1, DEG2, ES, ED, CNT, ROWPTR, FILL, ESRC, EWV, NORM, stream);

  k_minmax_init<<<1, 1, 0, stream>>>(MMX);
  k_score2<0><<<dim3(DIS_NN/128, MI_NN/128), 256, 0, stream>>>(FEA_MI, FEA_DIS, nullptr, MMX);
  k_score2<1><<<dim3(DIS_NN/128, MI_NN/128), 256, 0, stream>>>(FEA_MI, FEA_DIS, S, MMX);
}

// Round 3
// 688.472 us; speedup vs baseline: 2.4167x; 1.9002x over previous
//
#include <hip/hip_runtime.h>
#include <cstdint>
#include <cstddef>

#define MI_NN 16384
#define DIS_NN 8192
#define EMB 128
#define EMM (MI_NN*32)
#define EDD (DIS_NN*32)

typedef __attribute__((ext_vector_type(8))) short short8;
typedef __attribute__((ext_vector_type(4))) float f32x4;

__device__ __forceinline__ float leakyr(float x){ return x > 0.f ? x : 0.2f*x; }
__device__ __forceinline__ float eluf(float x){ return x > 0.f ? x : expm1f(x); }

__device__ __forceinline__ unsigned fenc(float f){
  unsigned u = __float_as_uint(f);
  return (u & 0x80000000u) ? ~u : (u | 0x80000000u);
}
__device__ __forceinline__ float fdec(unsigned u){
  unsigned b = (u & 0x80000000u) ? (u & 0x7FFFFFFFu) : ~u;
  return __uint_as_float(b);
}
__device__ __forceinline__ unsigned bf16u(float x){
  unsigned u = __float_as_uint(x);
  return (u + 0x7FFFu + ((u >> 16) & 1u)) >> 16;   // RNE
}

// ---------------- CSR build ----------------
__global__ __launch_bounds__(256) void k_count(const int* __restrict__ col,
                                               int* __restrict__ cnt, int E){
  int t = blockIdx.x*256 + threadIdx.x;
  if (t < E) atomicAdd(&cnt[col[t]], 1);
}

__global__ __launch_bounds__(1024) void k_scan(const int* __restrict__ cnt,
                                               int* __restrict__ rowptr, int n, int E){
  __shared__ int lds[1024];
  int t = threadIdx.x;
  int chunk = n >> 10;
  int base = t*chunk;
  int s = 0;
  for (int i = 0; i < chunk; ++i) s += cnt[base+i];
  lds[t] = s; __syncthreads();
  for (int off = 1; off < 1024; off <<= 1){
    int v = (t >= off) ? lds[t-off] : 0;
    __syncthreads();
    lds[t] += v;
    __syncthreads();
  }
  int run = lds[t] - s;
  for (int i = 0; i < chunk; ++i){ rowptr[base+i] = run; run += cnt[base+i]; }
  if (t == 0) rowptr[n] = E;
}

__global__ __launch_bounds__(256) void k_fill2(const int* __restrict__ row,
                                               const int* __restrict__ col,
                                               const float* __restrict__ ew,
                                               const int* __restrict__ rowptr,
                                               int* __restrict__ fill,
                                               int* __restrict__ esrc,
                                               float* __restrict__ ewv, int E){
  int t = blockIdx.x*256 + threadIdx.x;
  if (t < E){
    int c = col[t];
    int p = rowptr[c] + atomicAdd(&fill[c], 1);
    esrc[p] = row[t];
    ewv[p] = ew[t];
  }
}

// ---------------- dense h = x @ w  (n x 128 by 128 x 128, fp32) ----------------
__global__ __launch_bounds__(256) void k_gemm_xw(const float* __restrict__ X,
                                                 const float* __restrict__ W,
                                                 float* __restrict__ H, int n){
  __shared__ float wl[EMB*EMB];
  int t = threadIdx.x;
  {
    const float4* W4 = (const float4*)W;
    float4* L4 = (float4*)wl;
    #pragma unroll
    for (int i = 0; i < 16; ++i) L4[t + 256*i] = W4[t + 256*i];
  }
  __syncthreads();
  int jg = t & 31;
  int rg = t >> 5;
  int r0 = blockIdx.x*32 + rg*4;
  f32x4 acc0 = {0,0,0,0}, acc1 = {0,0,0,0}, acc2 = {0,0,0,0}, acc3 = {0,0,0,0};
  const float4* X4 = (const float4*)X;
  for (int k4 = 0; k4 < 32; ++k4){
    float4 x0 = X4[(size_t)(r0+0)*32 + k4];
    float4 x1 = X4[(size_t)(r0+1)*32 + k4];
    float4 x2 = X4[(size_t)(r0+2)*32 + k4];
    float4 x3 = X4[(size_t)(r0+3)*32 + k4];
#define GSTEP(c0,c1,c2,c3,kq) { f32x4 w4 = *(const f32x4*)&wl[(kq)*EMB + jg*4]; \
      acc0 += (c0)*w4; acc1 += (c1)*w4; acc2 += (c2)*w4; acc3 += (c3)*w4; }
    GSTEP(x0.x, x1.x, x2.x, x3.x, k4*4+0)
    GSTEP(x0.y, x1.y, x2.y, x3.y, k4*4+1)
    GSTEP(x0.z, x1.z, x2.z, x3.z, k4*4+2)
    GSTEP(x0.w, x1.w, x2.w, x3.w, k4*4+3)
#undef GSTEP
  }
  float* out = H + (size_t)r0*EMB + jg*4;
  *(f32x4*)(out)         = acc0;
  *(f32x4*)(out + EMB)   = acc1;
  *(f32x4*)(out + 2*EMB) = acc2;
  *(f32x4*)(out + 3*EMB) = acc3;
}

// ---------------- degree / per-edge norm prep ----------------
__global__ __launch_bounds__(256) void k_deg1(const int* __restrict__ rowptr,
                                              const float* __restrict__ ewv,
                                              float* __restrict__ dinv, int n){
  int wid = (int)((blockIdx.x*blockDim.x + threadIdx.x) >> 6);
  int lane = threadIdx.x & 63;
  if (wid >= n) return;
  int beg = rowptr[wid], end = rowptr[wid+1];
  float s = 0.f;
  for (int i = beg + lane; i < end; i += 64) s += ewv[i];
  #pragma unroll
  for (int off = 32; off; off >>= 1) s += __shfl_xor(s, off);
  if (lane == 0) dinv[wid] = rsqrtf(1.0f + s);
}

__global__ __launch_bounds__(256) void k_deg2(const int* __restrict__ rowptr,
                                              float* __restrict__ dinv, int n){
  int v = blockIdx.x*256 + threadIdx.x;
  if (v < n) dinv[v] = rsqrtf(1.0f + (float)(rowptr[v+1] - rowptr[v]));
}

__global__ __launch_bounds__(256) void k_edgenorm1(const int* __restrict__ esrc,
                                                   const float* __restrict__ ewv,
                                                   const float* __restrict__ dinv,
                                                   float* __restrict__ nrm, int E){
  int t = blockIdx.x*256 + threadIdx.x;
  if (t < E) nrm[t] = dinv[esrc[t]] * ewv[t];
}

__global__ __launch_bounds__(256) void k_edgenorm2(const int* __restrict__ esrc,
                                                   const float* __restrict__ dinv,
                                                   float* __restrict__ nrm, int E){
  int t = blockIdx.x*256 + threadIdx.x;
  if (t < E) nrm[t] = dinv[esrc[t]];
}

__global__ __launch_bounds__(256) void k_esv(const int* __restrict__ esrc,
                                             const float* __restrict__ es,
                                             float* __restrict__ esv, int E){
  int t = blockIdx.x*256 + threadIdx.x;
  if (t < E) esv[t] = es[esrc[t]];
}

// ---------------- GCN aggregation: wave per node ----------------
__global__ __launch_bounds__(256) void k_gcn_agg2(const float* __restrict__ H,
    const float* __restrict__ dinv, const int* __restrict__ rowptr,
    const int* __restrict__ esrc, const float* __restrict__ nrm,
    const float* __restrict__ bias,
    float* __restrict__ xnext, float* __restrict__ fea, int n, int femode){
  int wid = (int)((blockIdx.x*blockDim.x + threadIdx.x) >> 6);
  int lane = threadIdx.x & 63;
  if (wid >= n) return;
  int v = wid;
  const float2* H2 = (const float2*)H;
  float dv = dinv[v];
  float2 hv = H2[(size_t)v*64 + lane];
  float ax = dv*hv.x, ay = dv*hv.y;
  int beg = rowptr[v], end = rowptr[v+1];
  int i = beg;
  int e4 = beg + ((end - beg) & ~3);
  for (; i < e4; i += 4){
    int r0 = esrc[i], r1 = esrc[i+1], r2 = esrc[i+2], r3 = esrc[i+3];
    float n0 = nrm[i], n1 = nrm[i+1], n2 = nrm[i+2], n3 = nrm[i+3];
    float2 h0 = H2[(size_t)r0*64 + lane];
    float2 h1 = H2[(size_t)r1*64 + lane];
    float2 h2 = H2[(size_t)r2*64 + lane];
    float2 h3 = H2[(size_t)r3*64 + lane];
    ax += n0*h0.x + n1*h1.x + n2*h2.x + n3*h3.x;
    ay += n0*h0.y + n1*h1.y + n2*h2.y + n3*h3.y;
  }
  for (; i < end; ++i){
    int r = esrc[i];
    float nm = nrm[i];
    float2 hr = H2[(size_t)r*64 + lane];
    ax += nm*hr.x; ay += nm*hr.y;
  }
  float2 b2 = ((const float2*)bias)[lane];
  float ox = eluf(dv*ax + b2.x), oy = eluf(dv*ay + b2.y);
  ((float2*)xnext)[(size_t)v*64 + lane] = make_float2(ox, oy);
  float2* F2 = (float2*)fea;
  if (femode == 0){
    F2[(size_t)v*64 + lane] = make_float2(ox, oy);
  } else {
    float2 f = F2[(size_t)v*64 + lane];
    F2[(size_t)v*64 + lane] = make_float2(f.x + ox, f.y + oy);
  }
}

// ---------------- GAT: per-node src/dst scores ----------------
__global__ __launch_bounds__(256) void k_srcdst(const float* __restrict__ H,
    const float* __restrict__ asrc, const float* __restrict__ adst,
    float* __restrict__ es, float* __restrict__ ed, int n){
  int wid = (int)((blockIdx.x*blockDim.x + threadIdx.x) >> 6);
  int lane = threadIdx.x & 63;
  if (wid >= n) return;
  const float2* H2 = (const float2*)H;
  float2 hv = H2[(size_t)wid*64 + lane];
  float2 s2 = ((const float2*)asrc)[lane];
  float2 d2 = ((const float2*)adst)[lane];
  float ps = hv.x*s2.x + hv.y*s2.y;
  float pd = hv.x*d2.x + hv.y*d2.y;
  #pragma unroll
  for (int off = 32; off; off >>= 1){
    ps += __shfl_xor(ps, off);
    pd += __shfl_xor(pd, off);
  }
  if (lane == 0){ es[wid] = ps; ed[wid] = pd; }
}

// ---------------- GAT aggregation ----------------
__global__ __launch_bounds__(256) void k_gat_agg2(const float* __restrict__ H,
    const float* __restrict__ es, const float* __restrict__ ed,
    const int* __restrict__ rowptr, const int* __restrict__ esrc,
    const float* __restrict__ esv, const float* __restrict__ bias,
    float* __restrict__ fea, int n){
  int wid = (int)((blockIdx.x*blockDim.x + threadIdx.x) >> 6);
  int lane = threadIdx.x & 63;
  if (wid >= n) return;
  int v = wid;
  float edv = ed[v];
  float self_e = leakyr(es[v] + edv);
  int beg = rowptr[v], end = rowptr[v+1];
  float m = self_e;
  for (int i = beg + lane; i < end; i += 64)
    m = fmaxf(m, leakyr(esv[i] + edv));
  #pragma unroll
  for (int off = 32; off; off >>= 1) m = fmaxf(m, __shfl_xor(m, off));
  float s = 0.f;
  for (int i = beg + lane; i < end; i += 64)
    s += expf(leakyr(esv[i] + edv) - m);
  #pragma unroll
  for (int off = 32; off; off >>= 1) s += __shfl_xor(s, off);
  s += expf(self_e - m);
  float inv_s = 1.0f / s;
  const float2* H2 = (const float2*)H;
  float2 hv = H2[(size_t)v*64 + lane];
  float a0 = expf(self_e - m)*inv_s;
  float ax = a0*hv.x, ay = a0*hv.y;
  int i = beg;
  int e4 = beg + ((end - beg) & ~3);
  for (; i < e4; i += 4){
    int r0 = esrc[i], r1 = esrc[i+1], r2 = esrc[i+2], r3 = esrc[i+3];
    float a_0 = expf(leakyr(esv[i]   + edv) - m)*inv_s;
    float a_1 = expf(leakyr(esv[i+1] + edv) - m)*inv_s;
    float a_2 = expf(leakyr(esv[i+2] + edv) - m)*inv_s;
    float a_3 = expf(leakyr(esv[i+3] + edv) - m)*inv_s;
    float2 h0 = H2[(size_t)r0*64 + lane];
    float2 h1 = H2[(size_t)r1*64 + lane];
    float2 h2 = H2[(size_t)r2*64 + lane];
    float2 h3 = H2[(size_t)r3*64 + lane];
    ax += a_0*h0.x + a_1*h1.x + a_2*h2.x + a_3*h3.x;
    ay += a_0*h0.y + a_1*h1.y + a_2*h2.y + a_3*h3.y;
  }
  for (; i < end; ++i){
    int r = esrc[i];
    float a = expf(leakyr(esv[i] + edv) - m)*inv_s;
    float2 hr = H2[(size_t)r*64 + lane];
    ax += a*hr.x; ay += a*hr.y;
  }
  float2 b2 = ((const float2*)bias)[lane];
  float ox = eluf(ax + b2.x), oy = eluf(ay + b2.y);
  float2* F2 = (float2*)fea;
  float2 f = F2[(size_t)v*64 + lane];
  F2[(size_t)v*64 + lane] = make_float2((f.x + ox)/3.0f, (f.y + oy)/3.0f);
}

// ---------------- fp32 -> bf16 pre-convert ----------------
__global__ __launch_bounds__(256) void k_tobf16(const float* __restrict__ X,
                                                ushort* __restrict__ Y, int n8){
  int i = blockIdx.x*256 + threadIdx.x;
  if (i >= n8) return;
  const float4* X4 = (const float4*)X;
  float4 a = X4[(size_t)i*2], b = X4[(size_t)i*2+1];
  union { ushort u[8]; uint4 v; } r;
  r.u[0]=(ushort)bf16u(a.x); r.u[1]=(ushort)bf16u(a.y);
  r.u[2]=(ushort)bf16u(a.z); r.u[3]=(ushort)bf16u(a.w);
  r.u[4]=(ushort)bf16u(b.x); r.u[5]=(ushort)bf16u(b.y);
  r.u[6]=(ushort)bf16u(b.z); r.u[7]=(ushort)bf16u(b.w);
  ((uint4*)Y)[i] = r.v;
}

// ---------------- score GEMM v3: bf16 inputs, multi-j-tile, gload_lds ----------------
// LDS tiles 128x128 bf16, XOR-swizzle byte^=((row&7)<<4); source pre-swizzled so
// global_load_lds's linear dest + swizzled ds_read form the involution (rule #21).
__device__ __forceinline__ void stage128(const uint8_t* G, uint8_t* L, int w, int lane){
  #pragma unroll
  for (int c = 0; c < 8; ++c){
    int linear = w*8192 + c*1024 + lane*16;
    int row = linear >> 8, col = linear & 255;
    const void* src = G + row*256 + (col ^ ((row & 7) << 4));
    __builtin_amdgcn_global_load_lds(
        (const __attribute__((address_space(1))) void*)src,
        (__attribute__((address_space(3))) void*)(L + w*8192 + c*1024),
        16, 0, 0);
  }
}

template<int STORE>
__global__ __launch_bounds__(256) void k_score3(const ushort* __restrict__ Abf,
                                                const ushort* __restrict__ Bbf,
                                                float* __restrict__ S,
                                                unsigned* __restrict__ mmx){
  __shared__ __align__(16) uint8_t Al[32768];
  __shared__ __align__(16) uint8_t Bl[32768];
  const int t = threadIdx.x;
  const int lane = t & 63;
  const int w = t >> 6;
  const int wr = w >> 1, wc = w & 1;
  const int lr = lane & 15, lk = lane >> 4;
  const int i0b = blockIdx.y * 128;
  const int jg  = blockIdx.x;                     // 8 groups of 8 j-tiles

  stage128((const uint8_t*)(Abf + (size_t)i0b*EMB), Al, w, lane);
  stage128((const uint8_t*)(Bbf + (size_t)(jg*8)*128*EMB), Bl, w, lane);
  __syncthreads();

  // A fragments held in registers for all 8 j-tiles
  short8 af[4][4];
  #pragma unroll
  for (int at = 0; at < 4; ++at){
    int ra = wr*64 + at*16 + lr;
    #pragma unroll
    for (int k0 = 0; k0 < 4; ++k0){
      int kb = k0*64 + lk*16;
      af[at][k0] = *(const short8*)&Al[ra*256 + (kb ^ ((ra & 7) << 4))];
    }
  }

  float mn = 0.f, sc = 0.f;
  if (STORE){
    mn = fdec(mmx[0]);
    float mx = fdec(mmx[1]);
    sc = (mx > mn) ? 1.0f/(mx - mn) : 0.0f;
  }
  float lmin = 3.4e38f, lmax = -3.4e38f;

  for (int jt = 0; jt < 8; ++jt){
    f32x4 acc[4][4];
    #pragma unroll
    for (int a = 0; a < 4; ++a)
      #pragma unroll
      for (int b = 0; b < 4; ++b) acc[a][b] = (f32x4){0.f,0.f,0.f,0.f};

    #pragma unroll
    for (int k0 = 0; k0 < 4; ++k0){
      int kb = k0*64 + lk*16;
      short8 bfr[4];
      #pragma unroll
      for (int ct = 0; ct < 4; ++ct){
        int rb = wc*64 + ct*16 + lr;
        bfr[ct] = *(const short8*)&Bl[rb*256 + (kb ^ ((rb & 7) << 4))];
      }
      #pragma unroll
      for (int at = 0; at < 4; ++at)
        #pragma unroll
        for (int ct = 0; ct < 4; ++ct)
          acc[at][ct] = __builtin_amdgcn_mfma_f32_16x16x32_bf16(af[at][k0], bfr[ct], acc[at][ct], 0, 0, 0);
    }

    int j0 = (jg*8 + jt)*128;
    if (STORE){
      #pragma unroll
      for (int at = 0; at < 4; ++at){
        #pragma unroll
        for (int ct = 0; ct < 4; ++ct){
          int colj = j0 + wc*64 + ct*16 + lr;
          int row0 = i0b + wr*64 + at*16 + lk*4;
          #pragma unroll
          for (int q = 0; q < 4; ++q){
            float vv = fminf(fmaxf((acc[at][ct][q] - mn)*sc, 0.f), 1.f);
            S[(size_t)(row0+q)*DIS_NN + colj] = vv;
          }
        }
      }
    } else {
      #pragma unroll
      for (int at = 0; at < 4; ++at)
        #pragma unroll
        for (int ct = 0; ct < 4; ++ct)
          #pragma unroll
          for (int q = 0; q < 4; ++q){
            float vv = acc[at][ct][q];
            lmin = fminf(lmin, vv); lmax = fmaxf(lmax, vv);
          }
    }
    __syncthreads();                 // all waves done reading Bl
    if (jt < 7){
      stage128((const uint8_t*)(Bbf + (size_t)(jg*8+jt+1)*128*EMB), Bl, w, lane);
      __syncthreads();
    }
  }

  if (!STORE){
    #pragma unroll
    for (int off = 32; off; off >>= 1){
      lmin = fminf(lmin, __shfl_xor(lmin, off));
      lmax = fmaxf(lmax, __shfl_xor(lmax, off));
    }
    if (lane == 0){
      atomicMin(&mmx[0], fenc(lmin));
      atomicMax(&mmx[1], fenc(lmax));
    }
  }
}

// ---------------- fallback score GEMM (fp32 direct, round-2 path) ----------------
template<int STORE>
__global__ __launch_bounds__(256) void k_score2(const float* __restrict__ A,
                                                const float* __restrict__ B,
                                                float* __restrict__ S,
                                                unsigned* __restrict__ mmx){
  __shared__ __align__(16) char Al[128*256];
  __shared__ __align__(16) char Bl[128*256];
  const int t = threadIdx.x;
  const int i0b = blockIdx.y*128;
  const int j0b = blockIdx.x*128;
  #pragma unroll
  for (int it = 0; it < 16; ++it){
    int f4 = it*256 + t;
    int row = f4 >> 5;
    int c4  = f4 & 31;
    float4 va = ((const float4*)(A + (size_t)(i0b+row)*EMB))[c4];
    float4 vb = ((const float4*)(B + (size_t)(j0b+row)*EMB))[c4];
    int sw = (row & 7) << 4;
    int off = row*256 + ((c4*8) ^ sw);
    uint2 pa, pb;
    pa.x = bf16u(va.x) | (bf16u(va.y) << 16);
    pa.y = bf16u(va.z) | (bf16u(va.w) << 16);
    pb.x = bf16u(vb.x) | (bf16u(vb.y) << 16);
    pb.y = bf16u(vb.z) | (bf16u(vb.w) << 16);
    *(uint2*)&Al[off] = pa;
    *(uint2*)&Bl[off] = pb;
  }
  __syncthreads();
  const int lane = t & 63;
  const int w = t >> 6;
  const int wr = w >> 1, wc = w & 1;
  const int lr = lane & 15;
  const int lk = lane >> 4;
  f32x4 acc[4][4];
  #pragma unroll
  for (int a = 0; a < 4; ++a)
    #pragma unroll
    for (int b = 0; b < 4; ++b) acc[a][b] = (f32x4){0.f,0.f,0.f,0.f};
  #pragma unroll
  for (int k0 = 0; k0 < 4; ++k0){
    int kb = k0*64 + lk*16;
    short8 af[4], bf[4];
    #pragma unroll
    for (int tt = 0; tt < 4; ++tt){
      int ra = wr*64 + tt*16 + lr;
      int rb = wc*64 + tt*16 + lr;
      af[tt] = *(const short8*)&Al[ra*256 + (kb ^ ((ra&7)<<4))];
      bf[tt] = *(const short8*)&Bl[rb*256 + (kb ^ ((rb&7)<<4))];
    }
    #pragma unroll
    for (int rt = 0; rt < 4; ++rt)
      #pragma unroll
      for (int ct = 0; ct < 4; ++ct)
        acc[rt][ct] = __builtin_amdgcn_mfma_f32_16x16x32_bf16(af[rt], bf[ct], acc[rt][ct], 0, 0, 0);
  }
  if (STORE){
    float mn = fdec(mmx[0]);
    float mx = fdec(mmx[1]);
    float sc = (mx > mn) ? 1.0f/(mx - mn) : 0.0f;
    int i0 = i0b + wr*64, j0 = j0b + wc*64;
    #pragma unroll
    for (int rt = 0; rt < 4; ++rt){
      #pragma unroll
      for (int ct = 0; ct < 4; ++ct){
        int colj = j0 + ct*16 + lr;
        int row0 = i0 + rt*16 + lk*4;
        #pragma unroll
        for (int q = 0; q < 4; ++q){
          float vv = fminf(fmaxf((acc[rt][ct][q] - mn)*sc, 0.f), 1.f);
          S[(size_t)(row0+q)*DIS_NN + colj] = vv;
        }
      }
    }
  } else {
    float lmin = 3.4e38f, lmax = -3.4e38f;
    #pragma unroll
    for (int rt = 0; rt < 4; ++rt)
      #pragma unroll
      for (int ct = 0; ct < 4; ++ct)
        #pragma unroll
        for (int q = 0; q < 4; ++q){
          float vv = acc[rt][ct][q];
          lmin = fminf(lmin, vv); lmax = fmaxf(lmax, vv);
        }
    #pragma unroll
    for (int off = 32; off; off >>= 1){
      lmin = fminf(lmin, __shfl_xor(lmin, off));
      lmax = fmaxf(lmax, __shfl_xor(lmax, off));
    }
    if (lane == 0){
      atomicMin(&mmx[0], fenc(lmin));
      atomicMax(&mmx[1], fenc(lmax));
    }
  }
}

__global__ void k_minmax_init(unsigned* mmx){
  mmx[0] = 0xFFFFFFFFu;
  mmx[1] = 0u;
}

// ---------------- host ----------------
struct GraphPtrs {
  const float *x0, *ew, *w1, *b1, *w2, *b2, *w3, *asrc, *adst, *b3;
  const int* edges;
  float* fea;
  int n, E;
};

static void run_graph(const GraphPtrs& g, float* A0, float* A1, float* Hb,
                      float* DEG1, float* DEG2, float* ES, float* ED,
                      int* CNT, int* ROWPTR, int* FILL,
                      int* ESRC, float* EWV, float* NORM,
                      hipStream_t stream){
  const int n = g.n, E = g.E;
  const int* erow = g.edges;
  const int* ecol = g.edges + E;
  hipMemsetAsync(CNT, 0, (size_t)n*sizeof(int), stream);
  k_count<<<(E+255)/256, 256, 0, stream>>>(ecol, CNT, E);
  k_scan<<<1, 1024, 0, stream>>>(CNT, ROWPTR, n, E);
  hipMemsetAsync(FILL, 0, (size_t)n*sizeof(int), stream);
  k_fill2<<<(E+255)/256, 256, 0, stream>>>(erow, ecol, g.ew, ROWPTR, FILL, ESRC, EWV, E);
  k_gemm_xw<<<n/32, 256, 0, stream>>>(g.x0, g.w1, Hb, n);
  k_deg1<<<n/4, 256, 0, stream>>>(ROWPTR, EWV, DEG1, n);
  k_edgenorm1<<<(E+255)/256, 256, 0, stream>>>(ESRC, EWV, DEG1, NORM, E);
  k_gcn_agg2<<<n/4, 256, 0, stream>>>(Hb, DEG1, ROWPTR, ESRC, NORM, g.b1, A0, g.fea, n, 0);
  k_gemm_xw<<<n/32, 256, 0, stream>>>(A0, g.w2, Hb, n);
  k_deg2<<<(n+255)/256, 256, 0, stream>>>(ROWPTR, DEG2, n);
  k_edgenorm2<<<(E+255)/256, 256, 0, stream>>>(ESRC, DEG2, NORM, E);
  k_gcn_agg2<<<n/4, 256, 0, stream>>>(Hb, DEG2, ROWPTR, ESRC, NORM, g.b2, A1, g.fea, n, 1);
  k_gemm_xw<<<n/32, 256, 0, stream>>>(A1, g.w3, Hb, n);
  k_srcdst<<<n/4, 256, 0, stream>>>(Hb, g.asrc, g.adst, ES, ED, n);
  k_esv<<<(E+255)/256, 256, 0, stream>>>(ESRC, ES, NORM, E);
  k_gat_agg2<<<n/4, 256, 0, stream>>>(Hb, ES, ED, ROWPTR, ESRC, NORM, g.b3, g.fea, n);
}

extern "C" void kernel_launch(void* const* d_in, const int* in_sizes, int n_in,
                              void* d_out, int out_size, void* d_ws, size_t ws_size,
                              hipStream_t stream){
  (void)in_sizes; (void)n_in; (void)out_size;
  const float* mm_x0  = (const float*)d_in[0];
  const float* dd_x0  = (const float*)d_in[1];
  const float* w1_mm  = (const float*)d_in[2];
  const float* b1_mm  = (const float*)d_in[3];
  const float* w2_mm  = (const float*)d_in[4];
  const float* b2_mm  = (const float*)d_in[5];
  const float* w3_mm  = (const float*)d_in[6];
  const float* asrc_mm= (const float*)d_in[7];
  const float* adst_mm= (const float*)d_in[8];
  const float* b3_mm  = (const float*)d_in[9];
  const float* w1_dd  = (const float*)d_in[10];
  const float* b1_dd  = (const float*)d_in[11];
  const float* w2_dd  = (const float*)d_in[12];
  const float* b2_dd  = (const float*)d_in[13];
  const float* w3_dd  = (const float*)d_in[14];
  const float* asrc_dd= (const float*)d_in[15];
  const float* adst_dd= (const float*)d_in[16];
  const float* b3_dd  = (const float*)d_in[17];
  const float* mm_ew  = (const float*)d_in[18];
  const float* dd_ew  = (const float*)d_in[19];
  const int* mm_edges = (const int*)d_in[20];
  const int* dd_edges = (const int*)d_in[21];

  float* S = (float*)d_out;
  const size_t SLOT = (size_t)MI_NN * EMB;
  float* A0  = S;
  float* A1  = S + SLOT;
  float* Hb  = S + 2*SLOT;
  float* base = S + 3*SLOT;
  float* DEG1 = base;                     base += MI_NN;
  float* DEG2 = base;                     base += MI_NN;
  float* ES   = base;                     base += MI_NN;
  float* ED   = base;                     base += MI_NN;
  int* CNT    = (int*)base;               base += MI_NN + 64;
  int* ROWPTR = (int*)base;               base += MI_NN + 64;
  int* FILL   = (int*)base;               base += MI_NN + 64;
  int* ESRC   = (int*)base;               base += EMM;
  float* EWV  = base;                     base += EMM;
  float* NORM = base;                     base += EMM;
  float* FEA_MI  = S + (size_t)MI_NN * DIS_NN;
  float* FEA_DIS = FEA_MI + SLOT;
  unsigned* MMX = (unsigned*)d_ws;

  GraphPtrs gm{mm_x0, mm_ew, w1_mm, b1_mm, w2_mm, b2_mm, w3_mm, asrc_mm, adst_mm, b3_mm,
               mm_edges, FEA_MI, MI_NN, EMM};
  run_graph(gm, A0, A1, Hb, DEG1, DEG2, ES, ED, CNT, ROWPTR, FILL, ESRC, EWV, NORM, stream);

  GraphPtrs gd{dd_x0, dd_ew, w1_dd, b1_dd, w2_dd, b2_dd, w3_dd, asrc_dd, adst_dd, b3_dd,
               dd_edges, FEA_DIS, DIS_NN, EDD};
  run_graph(gd, A0, A1, Hb, DEG1, DEG2, ES, ED, CNT, ROWPTR, FILL, ESRC, EWV, NORM, stream);

  k_minmax_init<<<1, 1, 0, stream>>>(MMX);

  const size_t need = 256 + ((size_t)MI_NN + DIS_NN) * EMB * sizeof(ushort);
  if (ws_size >= need){
    ushort* Abf = (ushort*)((char*)d_ws + 256);
    ushort* Bbf = Abf + (size_t)MI_NN * EMB;
    k_tobf16<<<(MI_NN*EMB/8 + 255)/256, 256, 0, stream>>>(FEA_MI, Abf, MI_NN*EMB/8);
    k_tobf16<<<(DIS_NN*EMB/8 + 255)/256, 256, 0, stream>>>(FEA_DIS, Bbf, DIS_NN*EMB/8);
    k_score3<0><<<dim3(8, MI_NN/128), 256, 0, stream>>>(Abf, Bbf, nullptr, MMX);
    k_score3<1><<<dim3(8, MI_NN/128), 256, 0, stream>>>(Abf, Bbf, S, MMX);
  } else {
    k_score2<0><<<dim3(DIS_NN/128, MI_NN/128), 256, 0, stream>>>(FEA_MI, FEA_DIS, nullptr, MMX);
    k_score2<1><<<dim3(DIS_NN/128, MI_NN/128), 256, 0, stream>>>(FEA_MI, FEA_DIS, S, MMX);
  }
}

// Round 4
// 641.298 us; speedup vs baseline: 2.5945x; 1.0736x over previous
//
#include <hip/hip_runtime.h>
#include <cstdint>
#include <cstddef>

#define MI_NN 16384
#define DIS_NN 8192
#define EMB 128
#define EMM (MI_NN*32)
#define EDD (DIS_NN*32)

typedef __attribute__((ext_vector_type(8))) short short8;
typedef __attribute__((ext_vector_type(4))) float f32x4;

__device__ __forceinline__ float leakyr(float x){ return x > 0.f ? x : 0.2f*x; }
__device__ __forceinline__ float eluf(float x){ return x > 0.f ? x : expm1f(x); }

__device__ __forceinline__ unsigned fenc(float f){
  unsigned u = __float_as_uint(f);
  return (u & 0x80000000u) ? ~u : (u | 0x80000000u);
}
__device__ __forceinline__ float fdec(unsigned u){
  unsigned b = (u & 0x80000000u) ? (u & 0x7FFFFFFFu) : ~u;
  return __uint_as_float(b);
}
__device__ __forceinline__ unsigned bf16u(float x){
  unsigned u = __float_as_uint(x);
  return (u + 0x7FFFu + ((u >> 16) & 1u)) >> 16;   // RNE
}
// unpack a packed pair of bf16 (one dword) to two floats
__device__ __forceinline__ float bfl(unsigned p){ return __uint_as_float(p << 16); }
__device__ __forceinline__ float bfh(unsigned p){ return __uint_as_float(p & 0xFFFF0000u); }

// ---------------- CSR build ----------------
__global__ __launch_bounds__(256) void k_count(const int* __restrict__ col,
                                               int* __restrict__ cnt, int E){
  int t = blockIdx.x*256 + threadIdx.x;
  if (t < E) atomicAdd(&cnt[col[t]], 1);
}

__global__ __launch_bounds__(1024) void k_scan(const int* __restrict__ cnt,
                                               int* __restrict__ rowptr, int n, int E){
  __shared__ int lds[1024];
  int t = threadIdx.x;
  int chunk = n >> 10;
  int base = t*chunk;
  int s = 0;
  for (int i = 0; i < chunk; ++i) s += cnt[base+i];
  lds[t] = s; __syncthreads();
  for (int off = 1; off < 1024; off <<= 1){
    int v = (t >= off) ? lds[t-off] : 0;
    __syncthreads();
    lds[t] += v;
    __syncthreads();
  }
  int run = lds[t] - s;
  for (int i = 0; i < chunk; ++i){ rowptr[base+i] = run; run += cnt[base+i]; }
  if (t == 0) rowptr[n] = E;
}

__global__ __launch_bounds__(256) void k_fill2(const int* __restrict__ row,
                                               const int* __restrict__ col,
                                               const float* __restrict__ ew,
                                               const int* __restrict__ rowptr,
                                               int* __restrict__ fill,
                                               int* __restrict__ esrc,
                                               float* __restrict__ ewv, int E){
  int t = blockIdx.x*256 + threadIdx.x;
  if (t < E){
    int c = col[t];
    int p = rowptr[c] + atomicAdd(&fill[c], 1);
    esrc[p] = row[t];
    ewv[p] = ew[t];
  }
}

// ---------------- dense h = x @ w  (fp32 compute, bf16 out) ----------------
__global__ __launch_bounds__(256) void k_gemm_xw(const float* __restrict__ X,
                                                 const float* __restrict__ W,
                                                 ushort* __restrict__ H, int n){
  __shared__ float wl[EMB*EMB];
  int t = threadIdx.x;
  {
    const float4* W4 = (const float4*)W;
    float4* L4 = (float4*)wl;
    #pragma unroll
    for (int i = 0; i < 16; ++i) L4[t + 256*i] = W4[t + 256*i];
  }
  __syncthreads();
  int jg = t & 31;
  int rg = t >> 5;
  int r0 = blockIdx.x*32 + rg*4;
  f32x4 acc0 = {0,0,0,0}, acc1 = {0,0,0,0}, acc2 = {0,0,0,0}, acc3 = {0,0,0,0};
  const float4* X4 = (const float4*)X;
  for (int k4 = 0; k4 < 32; ++k4){
    float4 x0 = X4[(size_t)(r0+0)*32 + k4];
    float4 x1 = X4[(size_t)(r0+1)*32 + k4];
    float4 x2 = X4[(size_t)(r0+2)*32 + k4];
    float4 x3 = X4[(size_t)(r0+3)*32 + k4];
#define GSTEP(c0,c1,c2,c3,kq) { f32x4 w4 = *(const f32x4*)&wl[(kq)*EMB + jg*4]; \
      acc0 += (c0)*w4; acc1 += (c1)*w4; acc2 += (c2)*w4; acc3 += (c3)*w4; }
    GSTEP(x0.x, x1.x, x2.x, x3.x, k4*4+0)
    GSTEP(x0.y, x1.y, x2.y, x3.y, k4*4+1)
    GSTEP(x0.z, x1.z, x2.z, x3.z, k4*4+2)
    GSTEP(x0.w, x1.w, x2.w, x3.w, k4*4+3)
#undef GSTEP
  }
#define PACK2(o, a) { o.x = bf16u(a[0]) | (bf16u(a[1])<<16); o.y = bf16u(a[2]) | (bf16u(a[3])<<16); }
  uint2 o0, o1, o2, o3;
  PACK2(o0, acc0) PACK2(o1, acc1) PACK2(o2, acc2) PACK2(o3, acc3)
#undef PACK2
  ushort* out = H + (size_t)r0*EMB + jg*4;
  *(uint2*)(out)         = o0;
  *(uint2*)(out + EMB)   = o1;
  *(uint2*)(out + 2*EMB) = o2;
  *(uint2*)(out + 3*EMB) = o3;
}

// ---------------- degree ----------------
__global__ __launch_bounds__(256) void k_deg1(const int* __restrict__ rowptr,
                                              const float* __restrict__ ewv,
                                              float* __restrict__ dinv, int n){
  int wid = (int)((blockIdx.x*blockDim.x + threadIdx.x) >> 6);
  int lane = threadIdx.x & 63;
  if (wid >= n) return;
  int beg = rowptr[wid], end = rowptr[wid+1];
  float s = 0.f;
  for (int i = beg + lane; i < end; i += 64) s += ewv[i];
  #pragma unroll
  for (int off = 32; off; off >>= 1) s += __shfl_xor(s, off);
  if (lane == 0) dinv[wid] = rsqrtf(1.0f + s);
}

__global__ __launch_bounds__(256) void k_deg2(const int* __restrict__ rowptr,
                                              float* __restrict__ dinv, int n){
  int v = blockIdx.x*256 + threadIdx.x;
  if (v < n) dinv[v] = rsqrtf(1.0f + (float)(rowptr[v+1] - rowptr[v]));
}

// ---------------- GCN aggregation: wave per node, bf16 H, inline dinv gather ----------------
__global__ __launch_bounds__(256) void k_gcn_agg3(const ushort* __restrict__ H,
    const float* __restrict__ dinv, const int* __restrict__ rowptr,
    const int* __restrict__ esrc, const float* __restrict__ ewv,
    const float* __restrict__ bias,
    float* __restrict__ xnext, float* __restrict__ fea, int n, int femode){
  int wid = (int)((blockIdx.x*blockDim.x + threadIdx.x) >> 6);
  int lane = threadIdx.x & 63;
  if (wid >= n) return;
  int v = wid;
  float dv = dinv[v];
  unsigned hb = *(const unsigned*)(H + (size_t)v*EMB + lane*2);
  float ax = dv*bfl(hb), ay = dv*bfh(hb);
  int beg = rowptr[v], end = rowptr[v+1];
  int i = beg;
  int e4 = beg + ((end - beg) & ~3);
  for (; i < e4; i += 4){
    int r0 = esrc[i], r1 = esrc[i+1], r2 = esrc[i+2], r3 = esrc[i+3];
    float n0 = dinv[r0], n1 = dinv[r1], n2 = dinv[r2], n3 = dinv[r3];
    if (ewv){ n0 *= ewv[i]; n1 *= ewv[i+1]; n2 *= ewv[i+2]; n3 *= ewv[i+3]; }
    unsigned h0 = *(const unsigned*)(H + (size_t)r0*EMB + lane*2);
    unsigned h1 = *(const unsigned*)(H + (size_t)r1*EMB + lane*2);
    unsigned h2 = *(const unsigned*)(H + (size_t)r2*EMB + lane*2);
    unsigned h3 = *(const unsigned*)(H + (size_t)r3*EMB + lane*2);
    ax += n0*bfl(h0) + n1*bfl(h1) + n2*bfl(h2) + n3*bfl(h3);
    ay += n0*bfh(h0) + n1*bfh(h1) + n2*bfh(h2) + n3*bfh(h3);
  }
  for (; i < end; ++i){
    int r = esrc[i];
    float nm = dinv[r];
    if (ewv) nm *= ewv[i];
    unsigned hr = *(const unsigned*)(H + (size_t)r*EMB + lane*2);
    ax += nm*bfl(hr); ay += nm*bfh(hr);
  }
  float2 b2 = ((const float2*)bias)[lane];
  float ox = eluf(dv*ax + b2.x), oy = eluf(dv*ay + b2.y);
  ((float2*)xnext)[(size_t)v*64 + lane] = make_float2(ox, oy);
  float2* F2 = (float2*)fea;
  if (femode == 0){
    F2[(size_t)v*64 + lane] = make_float2(ox, oy);
  } else {
    float2 f = F2[(size_t)v*64 + lane];
    F2[(size_t)v*64 + lane] = make_float2(f.x + ox, f.y + oy);
  }
}

// ---------------- GAT: per-node src/dst scores (bf16 H) ----------------
__global__ __launch_bounds__(256) void k_srcdst(const ushort* __restrict__ H,
    const float* __restrict__ asrc, const float* __restrict__ adst,
    float* __restrict__ es, float* __restrict__ ed, int n){
  int wid = (int)((blockIdx.x*blockDim.x + threadIdx.x) >> 6);
  int lane = threadIdx.x & 63;
  if (wid >= n) return;
  unsigned hb = *(const unsigned*)(H + (size_t)wid*EMB + lane*2);
  float hx = bfl(hb), hy = bfh(hb);
  float2 s2 = ((const float2*)asrc)[lane];
  float2 d2 = ((const float2*)adst)[lane];
  float ps = hx*s2.x + hy*s2.y;
  float pd = hx*d2.x + hy*d2.y;
  #pragma unroll
  for (int off = 32; off; off >>= 1){
    ps += __shfl_xor(ps, off);
    pd += __shfl_xor(pd, off);
  }
  if (lane == 0){ es[wid] = ps; ed[wid] = pd; }
}

// ---------------- GAT aggregation: 2 passes, online softmax, bf16 H ----------------
__global__ __launch_bounds__(256) void k_gat_agg3(const ushort* __restrict__ H,
    const float* __restrict__ es, const float* __restrict__ ed,
    const int* __restrict__ rowptr, const int* __restrict__ esrc,
    const float* __restrict__ bias,
    float* __restrict__ fea, int n){
  int wid = (int)((blockIdx.x*blockDim.x + threadIdx.x) >> 6);
  int lane = threadIdx.x & 63;
  if (wid >= n) return;
  int v = wid;
  float edv = ed[v];
  float self_e = leakyr(es[v] + edv);
  int beg = rowptr[v], end = rowptr[v+1];
  // pass 1: per-lane online max+sum over strided edges
  float m = -3.4e38f, s = 0.f;
  for (int i = beg + lane; i < end; i += 64){
    float e = leakyr(es[esrc[i]] + edv);
    if (e > m){ s = s*expf(m - e) + 1.0f; m = e; }
    else s += expf(e - m);
  }
  // cross-lane merge
  #pragma unroll
  for (int off = 32; off; off >>= 1){
    float m2 = __shfl_xor(m, off), s2 = __shfl_xor(s, off);
    float mn_ = fmaxf(m, m2);
    s = s*expf(m - mn_) + s2*expf(m2 - mn_);
    m = mn_;
  }
  // fold in self loop
  {
    float mn_ = fmaxf(m, self_e);
    s = s*expf(m - mn_) + expf(self_e - mn_);
    m = mn_;
  }
  float inv_s = 1.0f / s;
  // pass 2: features (lane = 2 channels), unrolled x4
  unsigned hb = *(const unsigned*)(H + (size_t)v*EMB + lane*2);
  float a0 = expf(self_e - m)*inv_s;
  float ax = a0*bfl(hb), ay = a0*bfh(hb);
  int i = beg;
  int e4 = beg + ((end - beg) & ~3);
  for (; i < e4; i += 4){
    int r0 = esrc[i], r1 = esrc[i+1], r2 = esrc[i+2], r3 = esrc[i+3];
    float a_0 = expf(leakyr(es[r0] + edv) - m)*inv_s;
    float a_1 = expf(leakyr(es[r1] + edv) - m)*inv_s;
    float a_2 = expf(leakyr(es[r2] + edv) - m)*inv_s;
    float a_3 = expf(leakyr(es[r3] + edv) - m)*inv_s;
    unsigned h0 = *(const unsigned*)(H + (size_t)r0*EMB + lane*2);
    unsigned h1 = *(const unsigned*)(H + (size_t)r1*EMB + lane*2);
    unsigned h2 = *(const unsigned*)(H + (size_t)r2*EMB + lane*2);
    unsigned h3 = *(const unsigned*)(H + (size_t)r3*EMB + lane*2);
    ax += a_0*bfl(h0) + a_1*bfl(h1) + a_2*bfl(h2) + a_3*bfl(h3);
    ay += a_0*bfh(h0) + a_1*bfh(h1) + a_2*bfh(h2) + a_3*bfh(h3);
  }
  for (; i < end; ++i){
    int r = esrc[i];
    float a = expf(leakyr(es[r] + edv) - m)*inv_s;
    unsigned hr = *(const unsigned*)(H + (size_t)r*EMB + lane*2);
    ax += a*bfl(hr); ay += a*bfh(hr);
  }
  float2 b2 = ((const float2*)bias)[lane];
  float ox = eluf(ax + b2.x), oy = eluf(ay + b2.y);
  float2* F2 = (float2*)fea;
  float2 f = F2[(size_t)v*64 + lane];
  F2[(size_t)v*64 + lane] = make_float2((f.x + ox)/3.0f, (f.y + oy)/3.0f);
}

// ---------------- fp32 -> bf16 pre-convert (+ minmax init) ----------------
__global__ __launch_bounds__(256) void k_tobf16(const float* __restrict__ X,
                                                ushort* __restrict__ Y, int n8,
                                                unsigned* __restrict__ mmx){
  int i = blockIdx.x*256 + threadIdx.x;
  if (i == 0){ mmx[0] = 0xFFFFFFFFu; mmx[1] = 0u; }
  if (i >= n8) return;
  const float4* X4 = (const float4*)X;
  float4 a = X4[(size_t)i*2], b = X4[(size_t)i*2+1];
  union { ushort u[8]; uint4 v; } r;
  r.u[0]=(ushort)bf16u(a.x); r.u[1]=(ushort)bf16u(a.y);
  r.u[2]=(ushort)bf16u(a.z); r.u[3]=(ushort)bf16u(a.w);
  r.u[4]=(ushort)bf16u(b.x); r.u[5]=(ushort)bf16u(b.y);
  r.u[6]=(ushort)bf16u(b.z); r.u[7]=(ushort)bf16u(b.w);
  ((uint4*)Y)[i] = r.v;
}

// ---------------- score GEMM v3: bf16 inputs, multi-j-tile, gload_lds ----------------
__device__ __forceinline__ void stage128(const uint8_t* G, uint8_t* L, int w, int lane){
  #pragma unroll
  for (int c = 0; c < 8; ++c){
    int linear = w*8192 + c*1024 + lane*16;
    int row = linear >> 8, col = linear & 255;
    const void* src = G + row*256 + (col ^ ((row & 7) << 4));
    __builtin_amdgcn_global_load_lds(
        (const __attribute__((address_space(1))) void*)src,
        (__attribute__((address_space(3))) void*)(L + w*8192 + c*1024),
        16, 0, 0);
  }
}

template<int STORE>
__global__ __launch_bounds__(256) void k_score3(const ushort* __restrict__ Abf,
                                                const ushort* __restrict__ Bbf,
                                                float* __restrict__ S,
                                                unsigned* __restrict__ mmx){
  __shared__ __align__(16) uint8_t Al[32768];
  __shared__ __align__(16) uint8_t Bl[32768];
  const int t = threadIdx.x;
  const int lane = t & 63;
  const int w = t >> 6;
  const int wr = w >> 1, wc = w & 1;
  const int lr = lane & 15, lk = lane >> 4;
  const int i0b = blockIdx.y * 128;
  const int jg  = blockIdx.x;

  stage128((const uint8_t*)(Abf + (size_t)i0b*EMB), Al, w, lane);
  stage128((const uint8_t*)(Bbf + (size_t)(jg*8)*128*EMB), Bl, w, lane);
  __syncthreads();

  short8 af[4][4];
  #pragma unroll
  for (int at = 0; at < 4; ++at){
    int ra = wr*64 + at*16 + lr;
    #pragma unroll
    for (int k0 = 0; k0 < 4; ++k0){
      int kb = k0*64 + lk*16;
      af[at][k0] = *(const short8*)&Al[ra*256 + (kb ^ ((ra & 7) << 4))];
    }
  }

  float mn = 0.f, sc = 0.f;
  if (STORE){
    mn = fdec(mmx[0]);
    float mx = fdec(mmx[1]);
    sc = (mx > mn) ? 1.0f/(mx - mn) : 0.0f;
  }
  float lmin = 3.4e38f, lmax = -3.4e38f;

  for (int jt = 0; jt < 8; ++jt){
    f32x4 acc[4][4];
    #pragma unroll
    for (int a = 0; a < 4; ++a)
      #pragma unroll
      for (int b = 0; b < 4; ++b) acc[a][b] = (f32x4){0.f,0.f,0.f,0.f};

    #pragma unroll
    for (int k0 = 0; k0 < 4; ++k0){
      int kb = k0*64 + lk*16;
      short8 bfr[4];
      #pragma unroll
      for (int ct = 0; ct < 4; ++ct){
        int rb = wc*64 + ct*16 + lr;
        bfr[ct] = *(const short8*)&Bl[rb*256 + (kb ^ ((rb & 7) << 4))];
      }
      #pragma unroll
      for (int at = 0; at < 4; ++at)
        #pragma unroll
        for (int ct = 0; ct < 4; ++ct)
          acc[at][ct] = __builtin_amdgcn_mfma_f32_16x16x32_bf16(af[at][k0], bfr[ct], acc[at][ct], 0, 0, 0);
    }

    int j0 = (jg*8 + jt)*128;
    if (STORE){
      #pragma unroll
      for (int at = 0; at < 4; ++at){
        #pragma unroll
        for (int ct = 0; ct < 4; ++ct){
          int colj = j0 + wc*64 + ct*16 + lr;
          int row0 = i0b + wr*64 + at*16 + lk*4;
          #pragma unroll
          for (int q = 0; q < 4; ++q){
            float vv = fminf(fmaxf((acc[at][ct][q] - mn)*sc, 0.f), 1.f);
            S[(size_t)(row0+q)*DIS_NN + colj] = vv;
          }
        }
      }
    } else {
      #pragma unroll
      for (int at = 0; at < 4; ++at)
        #pragma unroll
        for (int ct = 0; ct < 4; ++ct)
          #pragma unroll
          for (int q = 0; q < 4; ++q){
            float vv = acc[at][ct][q];
            lmin = fminf(lmin, vv); lmax = fmaxf(lmax, vv);
          }
    }
    __syncthreads();
    if (jt < 7){
      stage128((const uint8_t*)(Bbf + (size_t)(jg*8+jt+1)*128*EMB), Bl, w, lane);
      __syncthreads();
    }
  }

  if (!STORE){
    #pragma unroll
    for (int off = 32; off; off >>= 1){
      lmin = fminf(lmin, __shfl_xor(lmin, off));
      lmax = fmaxf(lmax, __shfl_xor(lmax, off));
    }
    if (lane == 0){
      atomicMin(&mmx[0], fenc(lmin));
      atomicMax(&mmx[1], fenc(lmax));
    }
  }
}

// ---------------- host ----------------
struct GraphPtrs {
  const float *x0, *ew, *w1, *b1, *w2, *b2, *w3, *asrc, *adst, *b3;
  const int* edges;
  float* fea;
  int n, E;
};

static void run_graph(const GraphPtrs& g, float* A0, float* A1, ushort* Hb,
                      float* DEG1, float* DEG2, float* ES, float* ED,
                      int* CNT, int* ROWPTR, int* FILL,
                      int* ESRC, float* EWV,
                      hipStream_t stream){
  const int n = g.n, E = g.E;
  const int* erow = g.edges;
  const int* ecol = g.edges + E;
  hipMemsetAsync(CNT, 0, (size_t)n*sizeof(int), stream);
  k_count<<<(E+255)/256, 256, 0, stream>>>(ecol, CNT, E);
  k_scan<<<1, 1024, 0, stream>>>(CNT, ROWPTR, n, E);
  hipMemsetAsync(FILL, 0, (size_t)n*sizeof(int), stream);
  k_fill2<<<(E+255)/256, 256, 0, stream>>>(erow, ecol, g.ew, ROWPTR, FILL, ESRC, EWV, E);
  // layer 1: GCN with edge weights
  k_gemm_xw<<<n/32, 256, 0, stream>>>(g.x0, g.w1, Hb, n);
  k_deg1<<<n/4, 256, 0, stream>>>(ROWPTR, EWV, DEG1, n);
  k_gcn_agg3<<<n/4, 256, 0, stream>>>(Hb, DEG1, ROWPTR, ESRC, EWV, g.b1, A0, g.fea, n, 0);
  // layer 2: GCN, unit weights
  k_gemm_xw<<<n/32, 256, 0, stream>>>(A0, g.w2, Hb, n);
  k_deg2<<<(n+255)/256, 256, 0, stream>>>(ROWPTR, DEG2, n);
  k_gcn_agg3<<<n/4, 256, 0, stream>>>(Hb, DEG2, ROWPTR, ESRC, nullptr, g.b2, A1, g.fea, n, 1);
  // layer 3: GAT
  k_gemm_xw<<<n/32, 256, 0, stream>>>(A1, g.w3, Hb, n);
  k_srcdst<<<n/4, 256, 0, stream>>>(Hb, g.asrc, g.adst, ES, ED, n);
  k_gat_agg3<<<n/4, 256, 0, stream>>>(Hb, ES, ED, ROWPTR, ESRC, g.b3, g.fea, n);
}

extern "C" void kernel_launch(void* const* d_in, const int* in_sizes, int n_in,
                              void* d_out, int out_size, void* d_ws, size_t ws_size,
                              hipStream_t stream){
  (void)in_sizes; (void)n_in; (void)out_size;
  const float* mm_x0  = (const float*)d_in[0];
  const float* dd_x0  = (const float*)d_in[1];
  const float* w1_mm  = (const float*)d_in[2];
  const float* b1_mm  = (const float*)d_in[3];
  const float* w2_mm  = (const float*)d_in[4];
  const float* b2_mm  = (const float*)d_in[5];
  const float* w3_mm  = (const float*)d_in[6];
  const float* asrc_mm= (const float*)d_in[7];
  const float* adst_mm= (const float*)d_in[8];
  const float* b3_mm  = (const float*)d_in[9];
  const float* w1_dd  = (const float*)d_in[10];
  const float* b1_dd  = (const float*)d_in[11];
  const float* w2_dd  = (const float*)d_in[12];
  const float* b2_dd  = (const float*)d_in[13];
  const float* w3_dd  = (const float*)d_in[14];
  const float* asrc_dd= (const float*)d_in[15];
  const float* adst_dd= (const float*)d_in[16];
  const float* b3_dd  = (const float*)d_in[17];
  const float* mm_ew  = (const float*)d_in[18];
  const float* dd_ew  = (const float*)d_in[19];
  const int* mm_edges = (const int*)d_in[20];
  const int* dd_edges = (const int*)d_in[21];

  float* S = (float*)d_out;
  const size_t SLOT = (size_t)MI_NN * EMB;
  float* A0  = S;
  float* A1  = S + SLOT;
  ushort* Hb = (ushort*)(S + 2*SLOT);
  float* base = S + 3*SLOT;
  float* DEG1 = base;                     base += MI_NN;
  float* DEG2 = base;                     base += MI_NN;
  float* ES   = base;                     base += MI_NN;
  float* ED   = base;                     base += MI_NN;
  int* CNT    = (int*)base;               base += MI_NN + 64;
  int* ROWPTR = (int*)base;               base += MI_NN + 64;
  int* FILL   = (int*)base;               base += MI_NN + 64;
  int* ESRC   = (int*)base;               base += EMM;
  float* EWV  = base;                     base += EMM;
  float* FEA_MI  = S + (size_t)MI_NN * DIS_NN;
  float* FEA_DIS = FEA_MI + SLOT;
  unsigned* MMX = (unsigned*)d_ws;

  GraphPtrs gm{mm_x0, mm_ew, w1_mm, b1_mm, w2_mm, b2_mm, w3_mm, asrc_mm, adst_mm, b3_mm,
               mm_edges, FEA_MI, MI_NN, EMM};
  run_graph(gm, A0, A1, Hb, DEG1, DEG2, ES, ED, CNT, ROWPTR, FILL, ESRC, EWV, stream);

  GraphPtrs gd{dd_x0, dd_ew, w1_dd, b1_dd, w2_dd, b2_dd, w3_dd, asrc_dd, adst_dd, b3_dd,
               dd_edges, FEA_DIS, DIS_NN, EDD};
  run_graph(gd, A0, A1, Hb, DEG1, DEG2, ES, ED, CNT, ROWPTR, FILL, ESRC, EWV, stream);

  ushort* Abf = (ushort*)((char*)d_ws + 256);
  ushort* Bbf = Abf + (size_t)MI_NN * EMB;
  // FEA_MI and FEA_DIS are contiguous: one fused convert (+ MMX init)
  k_tobf16<<<((MI_NN+DIS_NN)*EMB/8 + 255)/256, 256, 0, stream>>>(FEA_MI, Abf,
                                                                 (MI_NN+DIS_NN)*EMB/8, MMX);
  k_score3<0><<<dim3(8, MI_NN/128), 256, 0, stream>>>(Abf, Bbf, nullptr, MMX);
  k_score3<1><<<dim3(8, MI_NN/128), 256, 0, stream>>>(Abf, Bbf, S, MMX);
}

// Round 5
// 568.977 us; speedup vs baseline: 2.9243x; 1.1271x over previous
//
#include <hip/hip_runtime.h>
#include <cstdint>
#include <cstddef>

#define MI_NN 16384
#define DIS_NN 8192
#define EMB 128
#define EMM (MI_NN*32)
#define EDD (DIS_NN*32)

typedef __attribute__((ext_vector_type(8))) short short8;
typedef __attribute__((ext_vector_type(4))) float f32x4;

__device__ __forceinline__ float leakyr(float x){ return x > 0.f ? x : 0.2f*x; }
__device__ __forceinline__ float eluf(float x){ return x > 0.f ? x : expm1f(x); }

__device__ __forceinline__ unsigned bf16u(float x){
  unsigned u = __float_as_uint(x);
  return (u + 0x7FFFu + ((u >> 16) & 1u)) >> 16;   // RNE
}
// unpack a packed pair of bf16 (one dword) to two floats
__device__ __forceinline__ float bfl(unsigned p){ return __uint_as_float(p << 16); }
__device__ __forceinline__ float bfh(unsigned p){ return __uint_as_float(p & 0xFFFF0000u); }

// ---------------- CSR build ----------------
__global__ __launch_bounds__(256) void k_count(const int* __restrict__ col,
                                               int* __restrict__ cnt, int E){
  int t = blockIdx.x*256 + threadIdx.x;
  if (t < E) atomicAdd(&cnt[col[t]], 1);
}

__global__ __launch_bounds__(1024) void k_scan(const int* __restrict__ cnt,
                                               int* __restrict__ rowptr, int n, int E){
  __shared__ int lds[1024];
  int t = threadIdx.x;
  int chunk = n >> 10;
  int base = t*chunk;
  int s = 0;
  for (int i = 0; i < chunk; ++i) s += cnt[base+i];
  lds[t] = s; __syncthreads();
  for (int off = 1; off < 1024; off <<= 1){
    int v = (t >= off) ? lds[t-off] : 0;
    __syncthreads();
    lds[t] += v;
    __syncthreads();
  }
  int run = lds[t] - s;
  for (int i = 0; i < chunk; ++i){ rowptr[base+i] = run; run += cnt[base+i]; }
  if (t == 0) rowptr[n] = E;
}

__global__ __launch_bounds__(256) void k_fill2(const int* __restrict__ row,
                                               const int* __restrict__ col,
                                               const float* __restrict__ ew,
                                               const int* __restrict__ rowptr,
                                               int* __restrict__ fill,
                                               int* __restrict__ esrc,
                                               float* __restrict__ ewv, int E){
  int t = blockIdx.x*256 + threadIdx.x;
  if (t < E){
    int c = col[t];
    int p = rowptr[c] + atomicAdd(&fill[c], 1);
    esrc[p] = row[t];
    ewv[p] = ew[t];
  }
}

// ---------------- dense h = x @ w  (fp32 compute, bf16 out) ----------------
__global__ __launch_bounds__(256) void k_gemm_xw(const float* __restrict__ X,
                                                 const float* __restrict__ W,
                                                 ushort* __restrict__ H, int n){
  __shared__ float wl[EMB*EMB];
  int t = threadIdx.x;
  {
    const float4* W4 = (const float4*)W;
    float4* L4 = (float4*)wl;
    #pragma unroll
    for (int i = 0; i < 16; ++i) L4[t + 256*i] = W4[t + 256*i];
  }
  __syncthreads();
  int jg = t & 31;
  int rg = t >> 5;
  int r0 = blockIdx.x*32 + rg*4;
  f32x4 acc0 = {0,0,0,0}, acc1 = {0,0,0,0}, acc2 = {0,0,0,0}, acc3 = {0,0,0,0};
  const float4* X4 = (const float4*)X;
  for (int k4 = 0; k4 < 32; ++k4){
    float4 x0 = X4[(size_t)(r0+0)*32 + k4];
    float4 x1 = X4[(size_t)(r0+1)*32 + k4];
    float4 x2 = X4[(size_t)(r0+2)*32 + k4];
    float4 x3 = X4[(size_t)(r0+3)*32 + k4];
#define GSTEP(c0,c1,c2,c3,kq) { f32x4 w4 = *(const f32x4*)&wl[(kq)*EMB + jg*4]; \
      acc0 += (c0)*w4; acc1 += (c1)*w4; acc2 += (c2)*w4; acc3 += (c3)*w4; }
    GSTEP(x0.x, x1.x, x2.x, x3.x, k4*4+0)
    GSTEP(x0.y, x1.y, x2.y, x3.y, k4*4+1)
    GSTEP(x0.z, x1.z, x2.z, x3.z, k4*4+2)
    GSTEP(x0.w, x1.w, x2.w, x3.w, k4*4+3)
#undef GSTEP
  }
#define PACK2(o, a) { o.x = bf16u(a[0]) | (bf16u(a[1])<<16); o.y = bf16u(a[2]) | (bf16u(a[3])<<16); }
  uint2 o0, o1, o2, o3;
  PACK2(o0, acc0) PACK2(o1, acc1) PACK2(o2, acc2) PACK2(o3, acc3)
#undef PACK2
  ushort* out = H + (size_t)r0*EMB + jg*4;
  *(uint2*)(out)         = o0;
  *(uint2*)(out + EMB)   = o1;
  *(uint2*)(out + 2*EMB) = o2;
  *(uint2*)(out + 3*EMB) = o3;
}

// ---------------- degree ----------------
__global__ __launch_bounds__(256) void k_deg1(const int* __restrict__ rowptr,
                                              const float* __restrict__ ewv,
                                              float* __restrict__ dinv, int n){
  int wid = (int)((blockIdx.x*blockDim.x + threadIdx.x) >> 6);
  int lane = threadIdx.x & 63;
  if (wid >= n) return;
  int beg = rowptr[wid], end = rowptr[wid+1];
  float s = 0.f;
  for (int i = beg + lane; i < end; i += 64) s += ewv[i];
  #pragma unroll
  for (int off = 32; off; off >>= 1) s += __shfl_xor(s, off);
  if (lane == 0) dinv[wid] = rsqrtf(1.0f + s);
}

__global__ __launch_bounds__(256) void k_deg2(const int* __restrict__ rowptr,
                                              float* __restrict__ dinv, int n){
  int v = blockIdx.x*256 + threadIdx.x;
  if (v < n) dinv[v] = rsqrtf(1.0f + (float)(rowptr[v+1] - rowptr[v]));
}

// ---------------- GCN aggregation: wave per node, bf16 H, inline dinv gather ----------------
__global__ __launch_bounds__(256) void k_gcn_agg3(const ushort* __restrict__ H,
    const float* __restrict__ dinv, const int* __restrict__ rowptr,
    const int* __restrict__ esrc, const float* __restrict__ ewv,
    const float* __restrict__ bias,
    float* __restrict__ xnext, float* __restrict__ fea, int n, int femode){
  int wid = (int)((blockIdx.x*blockDim.x + threadIdx.x) >> 6);
  int lane = threadIdx.x & 63;
  if (wid >= n) return;
  int v = wid;
  float dv = dinv[v];
  unsigned hb = *(const unsigned*)(H + (size_t)v*EMB + lane*2);
  float ax = dv*bfl(hb), ay = dv*bfh(hb);
  int beg = rowptr[v], end = rowptr[v+1];
  int i = beg;
  int e4 = beg + ((end - beg) & ~3);
  for (; i < e4; i += 4){
    int r0 = esrc[i], r1 = esrc[i+1], r2 = esrc[i+2], r3 = esrc[i+3];
    float n0 = dinv[r0], n1 = dinv[r1], n2 = dinv[r2], n3 = dinv[r3];
    if (ewv){ n0 *= ewv[i]; n1 *= ewv[i+1]; n2 *= ewv[i+2]; n3 *= ewv[i+3]; }
    unsigned h0 = *(const unsigned*)(H + (size_t)r0*EMB + lane*2);
    unsigned h1 = *(const unsigned*)(H + (size_t)r1*EMB + lane*2);
    unsigned h2 = *(const unsigned*)(H + (size_t)r2*EMB + lane*2);
    unsigned h3 = *(const unsigned*)(H + (size_t)r3*EMB + lane*2);
    ax += n0*bfl(h0) + n1*bfl(h1) + n2*bfl(h2) + n3*bfl(h3);
    ay += n0*bfh(h0) + n1*bfh(h1) + n2*bfh(h2) + n3*bfh(h3);
  }
  for (; i < end; ++i){
    int r = esrc[i];
    float nm = dinv[r];
    if (ewv) nm *= ewv[i];
    unsigned hr = *(const unsigned*)(H + (size_t)r*EMB + lane*2);
    ax += nm*bfl(hr); ay += nm*bfh(hr);
  }
  float2 b2 = ((const float2*)bias)[lane];
  float ox = eluf(dv*ax + b2.x), oy = eluf(dv*ay + b2.y);
  ((float2*)xnext)[(size_t)v*64 + lane] = make_float2(ox, oy);
  float2* F2 = (float2*)fea;
  if (femode == 0){
    F2[(size_t)v*64 + lane] = make_float2(ox, oy);
  } else {
    float2 f = F2[(size_t)v*64 + lane];
    F2[(size_t)v*64 + lane] = make_float2(f.x + ox, f.y + oy);
  }
}

// ---------------- GAT: per-node src/dst scores (bf16 H) ----------------
__global__ __launch_bounds__(256) void k_srcdst(const ushort* __restrict__ H,
    const float* __restrict__ asrc, const float* __restrict__ adst,
    float* __restrict__ es, float* __restrict__ ed, int n){
  int wid = (int)((blockIdx.x*blockDim.x + threadIdx.x) >> 6);
  int lane = threadIdx.x & 63;
  if (wid >= n) return;
  unsigned hb = *(const unsigned*)(H + (size_t)wid*EMB + lane*2);
  float hx = bfl(hb), hy = bfh(hb);
  float2 s2 = ((const float2*)asrc)[lane];
  float2 d2 = ((const float2*)adst)[lane];
  float ps = hx*s2.x + hy*s2.y;
  float pd = hx*d2.x + hy*d2.y;
  #pragma unroll
  for (int off = 32; off; off >>= 1){
    ps += __shfl_xor(ps, off);
    pd += __shfl_xor(pd, off);
  }
  if (lane == 0){ es[wid] = ps; ed[wid] = pd; }
}

// ---------------- GAT aggregation: 2 passes, online softmax, bf16 H ----------------
__global__ __launch_bounds__(256) void k_gat_agg3(const ushort* __restrict__ H,
    const float* __restrict__ es, const float* __restrict__ ed,
    const int* __restrict__ rowptr, const int* __restrict__ esrc,
    const float* __restrict__ bias,
    float* __restrict__ fea, int n){
  int wid = (int)((blockIdx.x*blockDim.x + threadIdx.x) >> 6);
  int lane = threadIdx.x & 63;
  if (wid >= n) return;
  int v = wid;
  float edv = ed[v];
  float self_e = leakyr(es[v] + edv);
  int beg = rowptr[v], end = rowptr[v+1];
  float m = -3.4e38f, s = 0.f;
  for (int i = beg + lane; i < end; i += 64){
    float e = leakyr(es[esrc[i]] + edv);
    if (e > m){ s = s*expf(m - e) + 1.0f; m = e; }
    else s += expf(e - m);
  }
  #pragma unroll
  for (int off = 32; off; off >>= 1){
    float m2 = __shfl_xor(m, off), s2 = __shfl_xor(s, off);
    float mn_ = fmaxf(m, m2);
    s = s*expf(m - mn_) + s2*expf(m2 - mn_);
    m = mn_;
  }
  {
    float mn_ = fmaxf(m, self_e);
    s = s*expf(m - mn_) + expf(self_e - mn_);
    m = mn_;
  }
  float inv_s = 1.0f / s;
  unsigned hb = *(const unsigned*)(H + (size_t)v*EMB + lane*2);
  float a0 = expf(self_e - m)*inv_s;
  float ax = a0*bfl(hb), ay = a0*bfh(hb);
  int i = beg;
  int e4 = beg + ((end - beg) & ~3);
  for (; i < e4; i += 4){
    int r0 = esrc[i], r1 = esrc[i+1], r2 = esrc[i+2], r3 = esrc[i+3];
    float a_0 = expf(leakyr(es[r0] + edv) - m)*inv_s;
    float a_1 = expf(leakyr(es[r1] + edv) - m)*inv_s;
    float a_2 = expf(leakyr(es[r2] + edv) - m)*inv_s;
    float a_3 = expf(leakyr(es[r3] + edv) - m)*inv_s;
    unsigned h0 = *(const unsigned*)(H + (size_t)r0*EMB + lane*2);
    unsigned h1 = *(const unsigned*)(H + (size_t)r1*EMB + lane*2);
    unsigned h2 = *(const unsigned*)(H + (size_t)r2*EMB + lane*2);
    unsigned h3 = *(const unsigned*)(H + (size_t)r3*EMB + lane*2);
    ax += a_0*bfl(h0) + a_1*bfl(h1) + a_2*bfl(h2) + a_3*bfl(h3);
    ay += a_0*bfh(h0) + a_1*bfh(h1) + a_2*bfh(h2) + a_3*bfh(h3);
  }
  for (; i < end; ++i){
    int r = esrc[i];
    float a = expf(leakyr(es[r] + edv) - m)*inv_s;
    unsigned hr = *(const unsigned*)(H + (size_t)r*EMB + lane*2);
    ax += a*bfl(hr); ay += a*bfh(hr);
  }
  float2 b2 = ((const float2*)bias)[lane];
  float ox = eluf(ax + b2.x), oy = eluf(ay + b2.y);
  float2* F2 = (float2*)fea;
  float2 f = F2[(size_t)v*64 + lane];
  F2[(size_t)v*64 + lane] = make_float2((f.x + ox)/3.0f, (f.y + oy)/3.0f);
}

// ---------------- fp32 -> bf16 pre-convert ----------------
__global__ __launch_bounds__(256) void k_tobf16(const float* __restrict__ X,
                                                ushort* __restrict__ Y, int n8){
  int i = blockIdx.x*256 + threadIdx.x;
  if (i >= n8) return;
  const float4* X4 = (const float4*)X;
  float4 a = X4[(size_t)i*2], b = X4[(size_t)i*2+1];
  union { ushort u[8]; uint4 v; } r;
  r.u[0]=(ushort)bf16u(a.x); r.u[1]=(ushort)bf16u(a.y);
  r.u[2]=(ushort)bf16u(a.z); r.u[3]=(ushort)bf16u(a.w);
  r.u[4]=(ushort)bf16u(b.x); r.u[5]=(ushort)bf16u(b.y);
  r.u[6]=(ushort)bf16u(b.z); r.u[7]=(ushort)bf16u(b.w);
  ((uint4*)Y)[i] = r.v;
}

// ---------------- score GEMM v4: bf16 inputs, multi-j-tile, gload_lds ----------------
__device__ __forceinline__ void stage128(const uint8_t* G, uint8_t* L, int w, int lane){
  #pragma unroll
  for (int c = 0; c < 8; ++c){
    int linear = w*8192 + c*1024 + lane*16;
    int row = linear >> 8, col = linear & 255;
    const void* src = G + row*256 + (col ^ ((row & 7) << 4));
    __builtin_amdgcn_global_load_lds(
        (const __attribute__((address_space(1))) void*)src,
        (__attribute__((address_space(3))) void*)(L + w*8192 + c*1024),
        16, 0, 0);
  }
}

// STORE=0: per-block {min,max} partial into part[] (NO contended atomics).
// STORE=1: normalized store using mm[0]=min, mm[1]=max.
template<int STORE>
__global__ __launch_bounds__(256) void k_score4(const ushort* __restrict__ Abf,
                                                const ushort* __restrict__ Bbf,
                                                float* __restrict__ S,
                                                float* __restrict__ mmpart){
  __shared__ __align__(16) uint8_t Al[32768];
  __shared__ __align__(16) uint8_t Bl[32768];
  __shared__ float red[16];
  const int t = threadIdx.x;
  const int lane = t & 63;
  const int w = t >> 6;
  const int wr = w >> 1, wc = w & 1;
  const int lr = lane & 15, lk = lane >> 4;
  const int i0b = blockIdx.y * 128;
  const int jg  = blockIdx.x;

  stage128((const uint8_t*)(Abf + (size_t)i0b*EMB), Al, w, lane);
  stage128((const uint8_t*)(Bbf + (size_t)(jg*8)*128*EMB), Bl, w, lane);
  __syncthreads();

  short8 af[4][4];
  #pragma unroll
  for (int at = 0; at < 4; ++at){
    int ra = wr*64 + at*16 + lr;
    #pragma unroll
    for (int k0 = 0; k0 < 4; ++k0){
      int kb = k0*64 + lk*16;
      af[at][k0] = *(const short8*)&Al[ra*256 + (kb ^ ((ra & 7) << 4))];
    }
  }

  float mn = 0.f, sc = 0.f;
  if (STORE){
    mn = mmpart[0];
    float mx = mmpart[1];
    sc = (mx > mn) ? 1.0f/(mx - mn) : 0.0f;
  }
  float lmin = 3.4e38f, lmax = -3.4e38f;

  for (int jt = 0; jt < 8; ++jt){
    f32x4 acc[4][4];
    #pragma unroll
    for (int a = 0; a < 4; ++a)
      #pragma unroll
      for (int b = 0; b < 4; ++b) acc[a][b] = (f32x4){0.f,0.f,0.f,0.f};

    #pragma unroll
    for (int k0 = 0; k0 < 4; ++k0){
      int kb = k0*64 + lk*16;
      short8 bfr[4];
      #pragma unroll
      for (int ct = 0; ct < 4; ++ct){
        int rb = wc*64 + ct*16 + lr;
        bfr[ct] = *(const short8*)&Bl[rb*256 + (kb ^ ((rb & 7) << 4))];
      }
      #pragma unroll
      for (int at = 0; at < 4; ++at)
        #pragma unroll
        for (int ct = 0; ct < 4; ++ct)
          acc[at][ct] = __builtin_amdgcn_mfma_f32_16x16x32_bf16(af[at][k0], bfr[ct], acc[at][ct], 0, 0, 0);
    }

    int j0 = (jg*8 + jt)*128;
    if (STORE){
      #pragma unroll
      for (int at = 0; at < 4; ++at){
        #pragma unroll
        for (int ct = 0; ct < 4; ++ct){
          int colj = j0 + wc*64 + ct*16 + lr;
          int row0 = i0b + wr*64 + at*16 + lk*4;
          #pragma unroll
          for (int q = 0; q < 4; ++q){
            float vv = fminf(fmaxf((acc[at][ct][q] - mn)*sc, 0.f), 1.f);
            S[(size_t)(row0+q)*DIS_NN + colj] = vv;
          }
        }
      }
    } else {
      #pragma unroll
      for (int at = 0; at < 4; ++at)
        #pragma unroll
        for (int ct = 0; ct < 4; ++ct)
          #pragma unroll
          for (int q = 0; q < 4; ++q){
            float vv = acc[at][ct][q];
            lmin = fminf(lmin, vv); lmax = fmaxf(lmax, vv);
          }
    }
    __syncthreads();
    if (jt < 7){
      stage128((const uint8_t*)(Bbf + (size_t)(jg*8+jt+1)*128*EMB), Bl, w, lane);
      __syncthreads();
    }
  }

  if (!STORE){
    #pragma unroll
    for (int off = 32; off; off >>= 1){
      lmin = fminf(lmin, __shfl_xor(lmin, off));
      lmax = fmaxf(lmax, __shfl_xor(lmax, off));
    }
    if (lane == 0){ red[w*2] = lmin; red[w*2+1] = lmax; }
    __syncthreads();
    if (t == 0){
      float a = fminf(fminf(red[0], red[2]), fminf(red[4], red[6]));
      float b = fmaxf(fmaxf(red[1], red[3]), fmaxf(red[5], red[7]));
      int bid = blockIdx.y * 8 + blockIdx.x;      // gridDim.x == 8
      mmpart[2 + bid*2]     = a;
      mmpart[2 + bid*2 + 1] = b;
    }
  }
}

// reduce 1024 per-block partials -> mm[0]=min, mm[1]=max (single block)
__global__ __launch_bounds__(1024) void k_mmred(float* __restrict__ mm){
  __shared__ float2 red[16];
  int t = threadIdx.x;
  float mn = mm[2 + t*2];
  float mx = mm[2 + t*2 + 1];
  #pragma unroll
  for (int off = 32; off; off >>= 1){
    mn = fminf(mn, __shfl_xor(mn, off));
    mx = fmaxf(mx, __shfl_xor(mx, off));
  }
  if ((t & 63) == 0) red[t >> 6] = make_float2(mn, mx);
  __syncthreads();
  if (t == 0){
    float a = red[0].x, b = red[0].y;
    #pragma unroll
    for (int i = 1; i < 16; ++i){ a = fminf(a, red[i].x); b = fmaxf(b, red[i].y); }
    mm[0] = a; mm[1] = b;
  }
}

// ---------------- host ----------------
struct GraphPtrs {
  const float *x0, *ew, *w1, *b1, *w2, *b2, *w3, *asrc, *adst, *b3;
  const int* edges;
  float* fea;
  int n, E;
};

static void run_graph(const GraphPtrs& g, float* A0, float* A1, ushort* Hb,
                      float* DEG1, float* DEG2, float* ES, float* ED,
                      int* CNT, int* ROWPTR, int* FILL,
                      int* ESRC, float* EWV,
                      hipStream_t stream){
  const int n = g.n, E = g.E;
  const int* erow = g.edges;
  const int* ecol = g.edges + E;
  hipMemsetAsync(CNT, 0, (size_t)n*sizeof(int), stream);
  k_count<<<(E+255)/256, 256, 0, stream>>>(ecol, CNT, E);
  k_scan<<<1, 1024, 0, stream>>>(CNT, ROWPTR, n, E);
  hipMemsetAsync(FILL, 0, (size_t)n*sizeof(int), stream);
  k_fill2<<<(E+255)/256, 256, 0, stream>>>(erow, ecol, g.ew, ROWPTR, FILL, ESRC, EWV, E);
  // layer 1: GCN with edge weights
  k_gemm_xw<<<n/32, 256, 0, stream>>>(g.x0, g.w1, Hb, n);
  k_deg1<<<n/4, 256, 0, stream>>>(ROWPTR, EWV, DEG1, n);
  k_gcn_agg3<<<n/4, 256, 0, stream>>>(Hb, DEG1, ROWPTR, ESRC, EWV, g.b1, A0, g.fea, n, 0);
  // layer 2: GCN, unit weights
  k_gemm_xw<<<n/32, 256, 0, stream>>>(A0, g.w2, Hb, n);
  k_deg2<<<(n+255)/256, 256, 0, stream>>>(ROWPTR, DEG2, n);
  k_gcn_agg3<<<n/4, 256, 0, stream>>>(Hb, DEG2, ROWPTR, ESRC, nullptr, g.b2, A1, g.fea, n, 1);
  // layer 3: GAT
  k_gemm_xw<<<n/32, 256, 0, stream>>>(A1, g.w3, Hb, n);
  k_srcdst<<<n/4, 256, 0, stream>>>(Hb, g.asrc, g.adst, ES, ED, n);
  k_gat_agg3<<<n/4, 256, 0, stream>>>(Hb, ES, ED, ROWPTR, ESRC, g.b3, g.fea, n);
}

extern "C" void kernel_launch(void* const* d_in, const int* in_sizes, int n_in,
                              void* d_out, int out_size, void* d_ws, size_t ws_size,
                              hipStream_t stream){
  (void)in_sizes; (void)n_in; (void)out_size; (void)ws_size;
  const float* mm_x0  = (const float*)d_in[0];
  const float* dd_x0  = (const float*)d_in[1];
  const float* w1_mm  = (const float*)d_in[2];
  const float* b1_mm  = (const float*)d_in[3];
  const float* w2_mm  = (const float*)d_in[4];
  const float* b2_mm  = (const float*)d_in[5];
  const float* w3_mm  = (const float*)d_in[6];
  const float* asrc_mm= (const float*)d_in[7];
  const float* adst_mm= (const float*)d_in[8];
  const float* b3_mm  = (const float*)d_in[9];
  const float* w1_dd  = (const float*)d_in[10];
  const float* b1_dd  = (const float*)d_in[11];
  const float* w2_dd  = (const float*)d_in[12];
  const float* b2_dd  = (const float*)d_in[13];
  const float* w3_dd  = (const float*)d_in[14];
  const float* asrc_dd= (const float*)d_in[15];
  const float* adst_dd= (const float*)d_in[16];
  const float* b3_dd  = (const float*)d_in[17];
  const float* mm_ew  = (const float*)d_in[18];
  const float* dd_ew  = (const float*)d_in[19];
  const int* mm_edges = (const int*)d_in[20];
  const int* dd_edges = (const int*)d_in[21];

  float* S = (float*)d_out;
  const size_t SLOT = (size_t)MI_NN * EMB;
  float* A0  = S;
  float* A1  = S + SLOT;
  ushort* Hb = (ushort*)(S + 2*SLOT);
  float* base = S + 3*SLOT;
  float* DEG1 = base;                     base += MI_NN;
  float* DEG2 = base;                     base += MI_NN;
  float* ES   = base;                     base += MI_NN;
  float* ED   = base;                     base += MI_NN;
  int* CNT    = (int*)base;               base += MI_NN + 64;
  int* ROWPTR = (int*)base;               base += MI_NN + 64;
  int* FILL   = (int*)base;               base += MI_NN + 64;
  int* ESRC   = (int*)base;               base += EMM;
  float* EWV  = base;                     base += EMM;
  float* FEA_MI  = S + (size_t)MI_NN * DIS_NN;
  float* FEA_DIS = FEA_MI + SLOT;

  // ws layout: [0..2) mn/mx, [2..2050) per-block partials, then bf16 A,B
  float* MM = (float*)d_ws;
  ushort* Abf = (ushort*)((char*)d_ws + 16384);
  ushort* Bbf = Abf + (size_t)MI_NN * EMB;

  GraphPtrs gm{mm_x0, mm_ew, w1_mm, b1_mm, w2_mm, b2_mm, w3_mm, asrc_mm, adst_mm, b3_mm,
               mm_edges, FEA_MI, MI_NN, EMM};
  run_graph(gm, A0, A1, Hb, DEG1, DEG2, ES, ED, CNT, ROWPTR, FILL, ESRC, EWV, stream);

  GraphPtrs gd{dd_x0, dd_ew, w1_dd, b1_dd, w2_dd, b2_dd, w3_dd, asrc_dd, adst_dd, b3_dd,
               dd_edges, FEA_DIS, DIS_NN, EDD};
  run_graph(gd, A0, A1, Hb, DEG1, DEG2, ES, ED, CNT, ROWPTR, FILL, ESRC, EWV, stream);

  // FEA_MI and FEA_DIS are contiguous: one fused convert
  k_tobf16<<<((MI_NN+DIS_NN)*EMB/8 + 255)/256, 256, 0, stream>>>(FEA_MI, Abf,
                                                                 (MI_NN+DIS_NN)*EMB/8);
  k_score4<0><<<dim3(8, MI_NN/128), 256, 0, stream>>>(Abf, Bbf, nullptr, MM);
  k_mmred<<<1, 1024, 0, stream>>>(MM);
  k_score4<1><<<dim3(8, MI_NN/128), 256, 0, stream>>>(Abf, Bbf, S, MM);
}

// Round 6
// 453.743 us; speedup vs baseline: 3.6670x; 1.2540x over previous
//
#include <hip/hip_runtime.h>
#include <cstdint>
#include <cstddef>

#define MI_NN 16384
#define DIS_NN 8192
#define EMB 128
#define EMM (MI_NN*32)
#define EDD (DIS_NN*32)

typedef __attribute__((ext_vector_type(8))) short short8;
typedef __attribute__((ext_vector_type(4))) float f32x4;

__device__ __forceinline__ float leakyr(float x){ return x > 0.f ? x : 0.2f*x; }
__device__ __forceinline__ float eluf(float x){ return x > 0.f ? x : expm1f(x); }

__device__ __forceinline__ unsigned bf16u(float x){
  unsigned u = __float_as_uint(x);
  return (u + 0x7FFFu + ((u >> 16) & 1u)) >> 16;   // RNE
}
__device__ __forceinline__ float bfl(unsigned p){ return __uint_as_float(p << 16); }
__device__ __forceinline__ float bfh(unsigned p){ return __uint_as_float(p & 0xFFFF0000u); }

// ================= CSR build (merged MM+DD) =================
__global__ __launch_bounds__(256) void k_count2g(const int* __restrict__ c0, int* __restrict__ n0c,
                                                 int E0, int nb0,
                                                 const int* __restrict__ c1, int* __restrict__ n1c,
                                                 int E1){
  int b = blockIdx.x;
  const int* col; int* cnt; int E; int t;
  if (b < nb0){ col = c0; cnt = n0c; E = E0; t = b*256 + threadIdx.x; }
  else        { col = c1; cnt = n1c; E = E1; t = (b - nb0)*256 + threadIdx.x; }
  if (t < E) atomicAdd(&cnt[col[t]], 1);
}

__global__ __launch_bounds__(1024) void k_scan2g(const int* __restrict__ cnt0, int* __restrict__ rp0,
                                                 int n0, int E0,
                                                 const int* __restrict__ cnt1, int* __restrict__ rp1,
                                                 int n1, int E1){
  const int* cnt = blockIdx.x ? cnt1 : cnt0;
  int* rowptr    = blockIdx.x ? rp1  : rp0;
  int n          = blockIdx.x ? n1   : n0;
  int E          = blockIdx.x ? E1   : E0;
  __shared__ int lds[1024];
  int t = threadIdx.x;
  int chunk = n >> 10;
  int base = t*chunk;
  int s = 0;
  for (int i = 0; i < chunk; ++i) s += cnt[base+i];
  lds[t] = s; __syncthreads();
  for (int off = 1; off < 1024; off <<= 1){
    int v = (t >= off) ? lds[t-off] : 0;
    __syncthreads();
    lds[t] += v;
    __syncthreads();
  }
  int run = lds[t] - s;
  for (int i = 0; i < chunk; ++i){ rowptr[base+i] = run; run += cnt[base+i]; }
  if (t == 0) rowptr[n] = E;
}

__global__ __launch_bounds__(256) void k_fill2g(
    const int* __restrict__ r0a, const int* __restrict__ c0a, const float* __restrict__ w0a,
    const int* __restrict__ rp0, int* __restrict__ f0, int* __restrict__ s0, float* __restrict__ v0,
    int E0, int nb0,
    const int* __restrict__ r1a, const int* __restrict__ c1a, const float* __restrict__ w1a,
    const int* __restrict__ rp1, int* __restrict__ f1, int* __restrict__ s1, float* __restrict__ v1,
    int E1){
  int b = blockIdx.x;
  const int *row, *col; const float* ew; const int* rowptr;
  int *fill, *esrc; float* ewv; int E, t;
  if (b < nb0){ row=r0a; col=c0a; ew=w0a; rowptr=rp0; fill=f0; esrc=s0; ewv=v0; E=E0; t=b*256+threadIdx.x; }
  else        { row=r1a; col=c1a; ew=w1a; rowptr=rp1; fill=f1; esrc=s1; ewv=v1; E=E1; t=(b-nb0)*256+threadIdx.x; }
  if (t < E){
    int c = col[t];
    int p = rowptr[c] + atomicAdd(&fill[c], 1);
    esrc[p] = row[t];
    ewv[p] = ew[t];
  }
}

// ================= dense h = x @ w (fp32 compute, bf16 out), merged =================
__global__ __launch_bounds__(256) void k_gemm2g(const float* __restrict__ X0, const float* __restrict__ W0,
                                                ushort* __restrict__ H0, int nb0,
                                                const float* __restrict__ X1, const float* __restrict__ W1,
                                                ushort* __restrict__ H1){
  int b = blockIdx.x;
  const float *X, *W; ushort* H; int rb;
  if (b < nb0){ X = X0; W = W0; H = H0; rb = b; }
  else        { X = X1; W = W1; H = H1; rb = b - nb0; }
  __shared__ float wl[EMB*EMB];
  int t = threadIdx.x;
  {
    const float4* W4 = (const float4*)W;
    float4* L4 = (float4*)wl;
    #pragma unroll
    for (int i = 0; i < 16; ++i) L4[t + 256*i] = W4[t + 256*i];
  }
  __syncthreads();
  int jg = t & 31;
  int rg = t >> 5;
  int r0 = rb*32 + rg*4;
  f32x4 acc0 = {0,0,0,0}, acc1 = {0,0,0,0}, acc2 = {0,0,0,0}, acc3 = {0,0,0,0};
  const float4* X4 = (const float4*)X;
  for (int k4 = 0; k4 < 32; ++k4){
    float4 x0 = X4[(size_t)(r0+0)*32 + k4];
    float4 x1 = X4[(size_t)(r0+1)*32 + k4];
    float4 x2 = X4[(size_t)(r0+2)*32 + k4];
    float4 x3 = X4[(size_t)(r0+3)*32 + k4];
#define GSTEP(c0,c1,c2,c3,kq) { f32x4 w4 = *(const f32x4*)&wl[(kq)*EMB + jg*4]; \
      acc0 += (c0)*w4; acc1 += (c1)*w4; acc2 += (c2)*w4; acc3 += (c3)*w4; }
    GSTEP(x0.x, x1.x, x2.x, x3.x, k4*4+0)
    GSTEP(x0.y, x1.y, x2.y, x3.y, k4*4+1)
    GSTEP(x0.z, x1.z, x2.z, x3.z, k4*4+2)
    GSTEP(x0.w, x1.w, x2.w, x3.w, k4*4+3)
#undef GSTEP
  }
#define PACK2(o, a) { o.x = bf16u(a[0]) | (bf16u(a[1])<<16); o.y = bf16u(a[2]) | (bf16u(a[3])<<16); }
  uint2 o0, o1, o2, o3;
  PACK2(o0, acc0) PACK2(o1, acc1) PACK2(o2, acc2) PACK2(o3, acc3)
#undef PACK2
  ushort* out = H + (size_t)r0*EMB + jg*4;
  *(uint2*)(out)         = o0;
  *(uint2*)(out + EMB)   = o1;
  *(uint2*)(out + 2*EMB) = o2;
  *(uint2*)(out + 3*EMB) = o3;
}

// ================= degree, merged =================
__global__ __launch_bounds__(256) void k_deg1_2g(const int* __restrict__ rp0, const float* __restrict__ ew0,
                                                 float* __restrict__ d0, int n0, int nb0,
                                                 const int* __restrict__ rp1, const float* __restrict__ ew1,
                                                 float* __restrict__ d1, int n1){
  int b = blockIdx.x;
  const int* rowptr; const float* ewv; float* dinv; int n, wid;
  int lane = threadIdx.x & 63;
  if (b < nb0){ rowptr=rp0; ewv=ew0; dinv=d0; n=n0; wid = (b*256 + threadIdx.x) >> 6; }
  else        { rowptr=rp1; ewv=ew1; dinv=d1; n=n1; wid = ((b-nb0)*256 + threadIdx.x) >> 6; }
  if (wid >= n) return;
  int beg = rowptr[wid], end = rowptr[wid+1];
  float s = 0.f;
  for (int i = beg + lane; i < end; i += 64) s += ewv[i];
  #pragma unroll
  for (int off = 32; off; off >>= 1) s += __shfl_xor(s, off);
  if (lane == 0) dinv[wid] = rsqrtf(1.0f + s);
}

__global__ __launch_bounds__(256) void k_deg2_2g(const int* __restrict__ rp0, float* __restrict__ d0,
                                                 int n0, int nb0,
                                                 const int* __restrict__ rp1, float* __restrict__ d1,
                                                 int n1){
  int b = blockIdx.x;
  const int* rowptr; float* dinv; int n, v;
  if (b < nb0){ rowptr=rp0; dinv=d0; n=n0; v = b*256 + threadIdx.x; }
  else        { rowptr=rp1; dinv=d1; n=n1; v = (b-nb0)*256 + threadIdx.x; }
  if (v < n) dinv[v] = rsqrtf(1.0f + (float)(rowptr[v+1] - rowptr[v]));
}

// ================= GCN aggregation, merged =================
__global__ __launch_bounds__(256) void k_agg2g(
    const ushort* __restrict__ H0, const float* __restrict__ di0, const int* __restrict__ rp0,
    const int* __restrict__ sr0, const float* __restrict__ ew0, const float* __restrict__ bi0,
    float* __restrict__ xn0, float* __restrict__ fe0, int n0, int nb0,
    const ushort* __restrict__ H1, const float* __restrict__ di1, const int* __restrict__ rp1,
    const int* __restrict__ sr1, const float* __restrict__ ew1, const float* __restrict__ bi1,
    float* __restrict__ xn1, float* __restrict__ fe1, int n1,
    int femode){
  int b = blockIdx.x;
  const ushort* H; const float* dinv; const int* rowptr; const int* esrc;
  const float* ewv; const float* bias; float* xnext; float* fea; int n, wid;
  int lane = threadIdx.x & 63;
  if (b < nb0){ H=H0; dinv=di0; rowptr=rp0; esrc=sr0; ewv=ew0; bias=bi0; xnext=xn0; fea=fe0; n=n0;
                wid = (b*256 + threadIdx.x) >> 6; }
  else        { H=H1; dinv=di1; rowptr=rp1; esrc=sr1; ewv=ew1; bias=bi1; xnext=xn1; fea=fe1; n=n1;
                wid = ((b-nb0)*256 + threadIdx.x) >> 6; }
  if (wid >= n) return;
  int v = wid;
  float dv = dinv[v];
  unsigned hb = *(const unsigned*)(H + (size_t)v*EMB + lane*2);
  float ax = dv*bfl(hb), ay = dv*bfh(hb);
  int beg = rowptr[v], end = rowptr[v+1];
  int i = beg;
  int e4 = beg + ((end - beg) & ~3);
  for (; i < e4; i += 4){
    int r0 = esrc[i], r1 = esrc[i+1], r2 = esrc[i+2], r3 = esrc[i+3];
    float n0v = dinv[r0], n1v = dinv[r1], n2v = dinv[r2], n3v = dinv[r3];
    if (ewv){ n0v *= ewv[i]; n1v *= ewv[i+1]; n2v *= ewv[i+2]; n3v *= ewv[i+3]; }
    unsigned h0 = *(const unsigned*)(H + (size_t)r0*EMB + lane*2);
    unsigned h1 = *(const unsigned*)(H + (size_t)r1*EMB + lane*2);
    unsigned h2 = *(const unsigned*)(H + (size_t)r2*EMB + lane*2);
    unsigned h3 = *(const unsigned*)(H + (size_t)r3*EMB + lane*2);
    ax += n0v*bfl(h0) + n1v*bfl(h1) + n2v*bfl(h2) + n3v*bfl(h3);
    ay += n0v*bfh(h0) + n1v*bfh(h1) + n2v*bfh(h2) + n3v*bfh(h3);
  }
  for (; i < end; ++i){
    int r = esrc[i];
    float nm = dinv[r];
    if (ewv) nm *= ewv[i];
    unsigned hr = *(const unsigned*)(H + (size_t)r*EMB + lane*2);
    ax += nm*bfl(hr); ay += nm*bfh(hr);
  }
  float2 b2 = ((const float2*)bias)[lane];
  float ox = eluf(dv*ax + b2.x), oy = eluf(dv*ay + b2.y);
  ((float2*)xnext)[(size_t)v*64 + lane] = make_float2(ox, oy);
  float2* F2 = (float2*)fea;
  if (femode == 0){
    F2[(size_t)v*64 + lane] = make_float2(ox, oy);
  } else {
    float2 f = F2[(size_t)v*64 + lane];
    F2[(size_t)v*64 + lane] = make_float2(f.x + ox, f.y + oy);
  }
}

// ================= GAT src/dst scores, merged =================
__global__ __launch_bounds__(256) void k_srcdst2g(
    const ushort* __restrict__ H0, const float* __restrict__ as0, const float* __restrict__ ad0,
    float* __restrict__ es0, float* __restrict__ ed0, int n0, int nb0,
    const ushort* __restrict__ H1, const float* __restrict__ as1, const float* __restrict__ ad1,
    float* __restrict__ es1, float* __restrict__ ed1, int n1){
  int b = blockIdx.x;
  const ushort* H; const float *asr, *ads; float *es, *ed; int n, wid;
  int lane = threadIdx.x & 63;
  if (b < nb0){ H=H0; asr=as0; ads=ad0; es=es0; ed=ed0; n=n0; wid = (b*256 + threadIdx.x) >> 6; }
  else        { H=H1; asr=as1; ads=ad1; es=es1; ed=ed1; n=n1; wid = ((b-nb0)*256 + threadIdx.x) >> 6; }
  if (wid >= n) return;
  unsigned hb = *(const unsigned*)(H + (size_t)wid*EMB + lane*2);
  float hx = bfl(hb), hy = bfh(hb);
  float2 s2 = ((const float2*)asr)[lane];
  float2 d2 = ((const float2*)ads)[lane];
  float ps = hx*s2.x + hy*s2.y;
  float pd = hx*d2.x + hy*d2.y;
  #pragma unroll
  for (int off = 32; off; off >>= 1){
    ps += __shfl_xor(ps, off);
    pd += __shfl_xor(pd, off);
  }
  if (lane == 0){ es[wid] = ps; ed[wid] = pd; }
}

// ================= GAT aggregation + bf16 shadow write, merged =================
__global__ __launch_bounds__(256) void k_gat2g(
    const ushort* __restrict__ H0, const float* __restrict__ es0, const float* __restrict__ ed0,
    const int* __restrict__ rp0, const int* __restrict__ sr0, const float* __restrict__ bi0,
    float* __restrict__ fe0, unsigned* __restrict__ sh0, int n0, int nb0,
    const ushort* __restrict__ H1, const float* __restrict__ es1, const float* __restrict__ ed1,
    const int* __restrict__ rp1, const int* __restrict__ sr1, const float* __restrict__ bi1,
    float* __restrict__ fe1, unsigned* __restrict__ sh1, int n1){
  int b = blockIdx.x;
  const ushort* H; const float *es, *ed; const int *rowptr, *esrc; const float* bias;
  float* fea; unsigned* shadow; int n, wid;
  int lane = threadIdx.x & 63;
  if (b < nb0){ H=H0; es=es0; ed=ed0; rowptr=rp0; esrc=sr0; bias=bi0; fea=fe0; shadow=sh0; n=n0;
                wid = (b*256 + threadIdx.x) >> 6; }
  else        { H=H1; es=es1; ed=ed1; rowptr=rp1; esrc=sr1; bias=bi1; fea=fe1; shadow=sh1; n=n1;
                wid = ((b-nb0)*256 + threadIdx.x) >> 6; }
  if (wid >= n) return;
  int v = wid;
  float edv = ed[v];
  float self_e = leakyr(es[v] + edv);
  int beg = rowptr[v], end = rowptr[v+1];
  float m = -3.4e38f, s = 0.f;
  for (int i = beg + lane; i < end; i += 64){
    float e = leakyr(es[esrc[i]] + edv);
    if (e > m){ s = s*expf(m - e) + 1.0f; m = e; }
    else s += expf(e - m);
  }
  #pragma unroll
  for (int off = 32; off; off >>= 1){
    float m2 = __shfl_xor(m, off), s2 = __shfl_xor(s, off);
    float mn_ = fmaxf(m, m2);
    s = s*expf(m - mn_) + s2*expf(m2 - mn_);
    m = mn_;
  }
  {
    float mn_ = fmaxf(m, self_e);
    s = s*expf(m - mn_) + expf(self_e - mn_);
    m = mn_;
  }
  float inv_s = 1.0f / s;
  unsigned hb = *(const unsigned*)(H + (size_t)v*EMB + lane*2);
  float a0 = expf(self_e - m)*inv_s;
  float ax = a0*bfl(hb), ay = a0*bfh(hb);
  int i = beg;
  int e4 = beg + ((end - beg) & ~3);
  for (; i < e4; i += 4){
    int r0 = esrc[i], r1 = esrc[i+1], r2 = esrc[i+2], r3 = esrc[i+3];
    float a_0 = expf(leakyr(es[r0] + edv) - m)*inv_s;
    float a_1 = expf(leakyr(es[r1] + edv) - m)*inv_s;
    float a_2 = expf(leakyr(es[r2] + edv) - m)*inv_s;
    float a_3 = expf(leakyr(es[r3] + edv) - m)*inv_s;
    unsigned h0 = *(const unsigned*)(H + (size_t)r0*EMB + lane*2);
    unsigned h1 = *(const unsigned*)(H + (size_t)r1*EMB + lane*2);
    unsigned h2 = *(const unsigned*)(H + (size_t)r2*EMB + lane*2);
    unsigned h3 = *(const unsigned*)(H + (size_t)r3*EMB + lane*2);
    ax += a_0*bfl(h0) + a_1*bfl(h1) + a_2*bfl(h2) + a_3*bfl(h3);
    ay += a_0*bfh(h0) + a_1*bfh(h1) + a_2*bfh(h2) + a_3*bfh(h3);
  }
  for (; i < end; ++i){
    int r = esrc[i];
    float a = expf(leakyr(es[r] + edv) - m)*inv_s;
    unsigned hr = *(const unsigned*)(H + (size_t)r*EMB + lane*2);
    ax += a*bfl(hr); ay += a*bfh(hr);
  }
  float2 b2 = ((const float2*)bias)[lane];
  float ox = eluf(ax + b2.x), oy = eluf(ay + b2.y);
  float2* F2 = (float2*)fea;
  float2 f = F2[(size_t)v*64 + lane];
  float fx = (f.x + ox)/3.0f, fy = (f.y + oy)/3.0f;
  F2[(size_t)v*64 + lane] = make_float2(fx, fy);
  shadow[(size_t)v*64 + lane] = bf16u(fx) | (bf16u(fy) << 16);   // bf16 shadow for score GEMM
}

// ================= score GEMM v5: dbuf (A-LDS reused), 16 j-tiles/block =================
__device__ __forceinline__ void stage128(const uint8_t* G, uint8_t* L, int w, int lane){
  #pragma unroll
  for (int c = 0; c < 8; ++c){
    int linear = w*8192 + c*1024 + lane*16;
    int row = linear >> 8, col = linear & 255;
    const void* src = G + row*256 + (col ^ ((row & 7) << 4));
    __builtin_amdgcn_global_load_lds(
        (const __attribute__((address_space(1))) void*)src,
        (__attribute__((address_space(3))) void*)(L + w*8192 + c*1024),
        16, 0, 0);
  }
}

#define NT 16
template<int STORE>
__global__ __launch_bounds__(256) void k_score5(const ushort* __restrict__ Abf,
                                                const ushort* __restrict__ Bbf,
                                                float* __restrict__ S,
                                                float* __restrict__ mmpart){
  __shared__ __align__(16) uint8_t L0[32768];
  __shared__ __align__(16) uint8_t L1[32768];
  __shared__ float red[16];
  const int t = threadIdx.x;
  const int lane = t & 63;
  const int w = t >> 6;
  const int wr = w >> 1, wc = w & 1;
  const int lr = lane & 15, lk = lane >> 4;
  const int i0b = blockIdx.y * 128;
  const int jbase = blockIdx.x * NT;              // gridDim.x = DIS_NN/(128*NT) = 4

  stage128((const uint8_t*)(Abf + (size_t)i0b*EMB), L0, w, lane);
  stage128((const uint8_t*)(Bbf + (size_t)jbase*128*EMB), L1, w, lane);
  __syncthreads();

  // A fragments -> registers (L0 dead afterwards, reused as 2nd B buffer)
  short8 af[4][4];
  #pragma unroll
  for (int at = 0; at < 4; ++at){
    int ra = wr*64 + at*16 + lr;
    #pragma unroll
    for (int k0 = 0; k0 < 4; ++k0){
      int kb = k0*64 + lk*16;
      af[at][k0] = *(const short8*)&L0[ra*256 + (kb ^ ((ra & 7) << 4))];
    }
  }
  __syncthreads();                                // all waves done reading L0
  stage128((const uint8_t*)(Bbf + (size_t)(jbase+1)*128*EMB), L0, w, lane);

  float mn = 0.f, sc = 0.f;
  if (STORE){
    mn = mmpart[0];
    float mx = mmpart[1];
    sc = (mx > mn) ? 1.0f/(mx - mn) : 0.0f;
  }
  float lmin = 3.4e38f, lmax = -3.4e38f;

  for (int jt = 0; jt < NT; ++jt){
    uint8_t* curB = (jt & 1) ? L0 : L1;
    f32x4 acc[4][4];
    #pragma unroll
    for (int a = 0; a < 4; ++a)
      #pragma unroll
      for (int b = 0; b < 4; ++b) acc[a][b] = (f32x4){0.f,0.f,0.f,0.f};

    #pragma unroll
    for (int k0 = 0; k0 < 4; ++k0){
      int kb = k0*64 + lk*16;
      short8 bfr[4];
      #pragma unroll
      for (int ct = 0; ct < 4; ++ct){
        int rb = wc*64 + ct*16 + lr;
        bfr[ct] = *(const short8*)&curB[rb*256 + (kb ^ ((rb & 7) << 4))];
      }
      #pragma unroll
      for (int at = 0; at < 4; ++at)
        #pragma unroll
        for (int ct = 0; ct < 4; ++ct)
          acc[at][ct] = __builtin_amdgcn_mfma_f32_16x16x32_bf16(af[at][k0], bfr[ct], acc[at][ct], 0, 0, 0);
    }

    int j0 = (jbase + jt)*128;
    if (STORE){
      #pragma unroll
      for (int at = 0; at < 4; ++at){
        #pragma unroll
        for (int ct = 0; ct < 4; ++ct){
          int colj = j0 + wc*64 + ct*16 + lr;
          int row0 = i0b + wr*64 + at*16 + lk*4;
          #pragma unroll
          for (int q = 0; q < 4; ++q){
            float vv = fminf(fmaxf((acc[at][ct][q] - mn)*sc, 0.f), 1.f);
            S[(size_t)(row0+q)*DIS_NN + colj] = vv;
          }
        }
      }
    } else {
      #pragma unroll
      for (int at = 0; at < 4; ++at)
        #pragma unroll
        for (int ct = 0; ct < 4; ++ct)
          #pragma unroll
          for (int q = 0; q < 4; ++q){
            float vv = acc[at][ct][q];
            lmin = fminf(lmin, vv); lmax = fmaxf(lmax, vv);
          }
    }
    __syncthreads();                              // drains stage(jt+1); curB now free
    if (jt + 2 < NT)
      stage128((const uint8_t*)(Bbf + (size_t)(jbase+jt+2)*128*EMB), curB, w, lane);
  }

  if (!STORE){
    #pragma unroll
    for (int off = 32; off; off >>= 1){
      lmin = fminf(lmin, __shfl_xor(lmin, off));
      lmax = fmaxf(lmax, __shfl_xor(lmax, off));
    }
    if (lane == 0){ red[w*2] = lmin; red[w*2+1] = lmax; }
    __syncthreads();
    if (t == 0){
      float a = fminf(fminf(red[0], red[2]), fminf(red[4], red[6]));
      float b = fmaxf(fmaxf(red[1], red[3]), fmaxf(red[5], red[7]));
      int bid = blockIdx.y * 4 + blockIdx.x;      // 512 blocks
      mmpart[2 + bid*2]     = a;
      mmpart[2 + bid*2 + 1] = b;
    }
  }
}

// reduce 512 per-block partials -> mm[0]=min, mm[1]=max
__global__ __launch_bounds__(512) void k_mmred(float* __restrict__ mm){
  __shared__ float2 red[8];
  int t = threadIdx.x;
  float mn = mm[2 + t*2];
  float mx = mm[2 + t*2 + 1];
  #pragma unroll
  for (int off = 32; off; off >>= 1){
    mn = fminf(mn, __shfl_xor(mn, off));
    mx = fmaxf(mx, __shfl_xor(mx, off));
  }
  if ((t & 63) == 0) red[t >> 6] = make_float2(mn, mx);
  __syncthreads();
  if (t == 0){
    float a = red[0].x, b = red[0].y;
    #pragma unroll
    for (int i = 1; i < 8; ++i){ a = fminf(a, red[i].x); b = fmaxf(b, red[i].y); }
    mm[0] = a; mm[1] = b;
  }
}

// ================= host =================
extern "C" void kernel_launch(void* const* d_in, const int* in_sizes, int n_in,
                              void* d_out, int out_size, void* d_ws, size_t ws_size,
                              hipStream_t stream){
  (void)in_sizes; (void)n_in; (void)out_size; (void)ws_size;
  const float* mm_x0  = (const float*)d_in[0];
  const float* dd_x0  = (const float*)d_in[1];
  const float* w1_mm  = (const float*)d_in[2];
  const float* b1_mm  = (const float*)d_in[3];
  const float* w2_mm  = (const float*)d_in[4];
  const float* b2_mm  = (const float*)d_in[5];
  const float* w3_mm  = (const float*)d_in[6];
  const float* asrc_mm= (const float*)d_in[7];
  const float* adst_mm= (const float*)d_in[8];
  const float* b3_mm  = (const float*)d_in[9];
  const float* w1_dd  = (const float*)d_in[10];
  const float* b1_dd  = (const float*)d_in[11];
  const float* w2_dd  = (const float*)d_in[12];
  const float* b2_dd  = (const float*)d_in[13];
  const float* w3_dd  = (const float*)d_in[14];
  const float* asrc_dd= (const float*)d_in[15];
  const float* adst_dd= (const float*)d_in[16];
  const float* b3_dd  = (const float*)d_in[17];
  const float* mm_ew  = (const float*)d_in[18];
  const float* dd_ew  = (const float*)d_in[19];
  const int* mm_edges = (const int*)d_in[20];
  const int* dd_edges = (const int*)d_in[21];

  float* S = (float*)d_out;
  // scratch carved from score region (overwritten only by final store pass)
  float* p = S;
  float* A0m = p;  p += (size_t)MI_NN*EMB;
  float* A1m = p;  p += (size_t)MI_NN*EMB;
  float* A0d = p;  p += (size_t)DIS_NN*EMB;
  float* A1d = p;  p += (size_t)DIS_NN*EMB;
  ushort* Hbm = (ushort*)p; p += (size_t)MI_NN*EMB/2;
  ushort* Hbd = (ushort*)p; p += (size_t)DIS_NN*EMB/2;
  float* DEG1m = p; p += MI_NN;
  float* DEG2m = p; p += MI_NN;
  float* ESm   = p; p += MI_NN;
  float* EDm   = p; p += MI_NN;
  float* DEG1d = p; p += DIS_NN;
  float* DEG2d = p; p += DIS_NN;
  float* ESd   = p; p += DIS_NN;
  float* EDd   = p; p += DIS_NN;
  int* CNTm  = (int*)p; p += MI_NN;          // CNTm+CNTd contiguous (one memset)
  int* CNTd  = (int*)p; p += DIS_NN;
  int* FILLm = (int*)p; p += MI_NN;          // FILLm+FILLd contiguous
  int* FILLd = (int*)p; p += DIS_NN;
  int* RPm   = (int*)p; p += MI_NN + 64;
  int* RPd   = (int*)p; p += DIS_NN + 64;
  int* ESRCm = (int*)p; p += EMM;
  int* ESRCd = (int*)p; p += EDD;
  float* EWVm = p; p += EMM;
  float* EWVd = p; p += EDD;
  float* FEA_MI  = S + (size_t)MI_NN * DIS_NN;
  float* FEA_DIS = FEA_MI + (size_t)MI_NN*EMB;

  float* MM = (float*)d_ws;                  // [0,1] mn/mx; [2..1026) partials
  ushort* Abf = (ushort*)((char*)d_ws + 16384);
  ushort* Bbf = Abf + (size_t)MI_NN * EMB;

  const int* erow_m = mm_edges;
  const int* ecol_m = mm_edges + EMM;
  const int* erow_d = dd_edges;
  const int* ecol_d = dd_edges + EDD;

  // ---- CSR build (both graphs) ----
  hipMemsetAsync(CNTm, 0, (size_t)(MI_NN + DIS_NN)*sizeof(int), stream);
  k_count2g<<<EMM/256 + EDD/256, 256, 0, stream>>>(ecol_m, CNTm, EMM, EMM/256,
                                                   ecol_d, CNTd, EDD);
  k_scan2g<<<2, 1024, 0, stream>>>(CNTm, RPm, MI_NN, EMM, CNTd, RPd, DIS_NN, EDD);
  hipMemsetAsync(FILLm, 0, (size_t)(MI_NN + DIS_NN)*sizeof(int), stream);
  k_fill2g<<<EMM/256 + EDD/256, 256, 0, stream>>>(erow_m, ecol_m, mm_ew, RPm, FILLm, ESRCm, EWVm,
                                                  EMM, EMM/256,
                                                  erow_d, ecol_d, dd_ew, RPd, FILLd, ESRCd, EWVd,
                                                  EDD);
  const int GB = MI_NN/32 + DIS_NN/32;       // 768 gemm blocks
  const int AB = MI_NN/4 + DIS_NN/4;         // 6144 agg blocks
  // ---- layer 1: GCN with edge weights ----
  k_gemm2g<<<GB, 256, 0, stream>>>(mm_x0, w1_mm, Hbm, MI_NN/32, dd_x0, w1_dd, Hbd);
  k_deg1_2g<<<AB, 256, 0, stream>>>(RPm, EWVm, DEG1m, MI_NN, MI_NN/4, RPd, EWVd, DEG1d, DIS_NN);
  k_agg2g<<<AB, 256, 0, stream>>>(Hbm, DEG1m, RPm, ESRCm, EWVm, b1_mm, A0m, FEA_MI, MI_NN, MI_NN/4,
                                  Hbd, DEG1d, RPd, ESRCd, EWVd, b1_dd, A0d, FEA_DIS, DIS_NN, 0);
  // ---- layer 2: GCN, unit weights ----
  k_gemm2g<<<GB, 256, 0, stream>>>(A0m, w2_mm, Hbm, MI_NN/32, A0d, w2_dd, Hbd);
  k_deg2_2g<<<MI_NN/256 + DIS_NN/256, 256, 0, stream>>>(RPm, DEG2m, MI_NN, MI_NN/256,
                                                        RPd, DEG2d, DIS_NN);
  k_agg2g<<<AB, 256, 0, stream>>>(Hbm, DEG2m, RPm, ESRCm, nullptr, b2_mm, A1m, FEA_MI, MI_NN, MI_NN/4,
                                  Hbd, DEG2d, RPd, ESRCd, nullptr, b2_dd, A1d, FEA_DIS, DIS_NN, 1);
  // ---- layer 3: GAT ----
  k_gemm2g<<<GB, 256, 0, stream>>>(A1m, w3_mm, Hbm, MI_NN/32, A1d, w3_dd, Hbd);
  k_srcdst2g<<<AB, 256, 0, stream>>>(Hbm, asrc_mm, adst_mm, ESm, EDm, MI_NN, MI_NN/4,
                                     Hbd, asrc_dd, adst_dd, ESd, EDd, DIS_NN);
  k_gat2g<<<AB, 256, 0, stream>>>(Hbm, ESm, EDm, RPm, ESRCm, b3_mm, FEA_MI, (unsigned*)Abf, MI_NN, MI_NN/4,
                                  Hbd, ESd, EDd, RPd, ESRCd, b3_dd, FEA_DIS, (unsigned*)Bbf, DIS_NN);
  // ---- score: minmax pass, reduce, normalized store pass ----
  k_score5<0><<<dim3(DIS_NN/(128*NT), MI_NN/128), 256, 0, stream>>>(Abf, Bbf, nullptr, MM);
  k_mmred<<<1, 512, 0, stream>>>(MM);
  k_score5<1><<<dim3(DIS_NN/(128*NT), MI_NN/128), 256, 0, stream>>>(Abf, Bbf, S, MM);
}